// Round 1
// baseline (1696.760 us; speedup 1.0000x reference)
//
#include <hip/hip_runtime.h>
#include <hip/hip_bf16.h>
#include <math.h>

#define NC 24
#define NP 48
#define NI 6
#define BATCH 256
#define DIM 512
#define HID 512
#define NROW (NP*BATCH)       // 12288
#define NELEM (BATCH*DIM)     // 131072

typedef __bf16 bf16x8 __attribute__((ext_vector_type(8)));
typedef float f32x4 __attribute__((ext_vector_type(4)));
using bf16 = __hip_bfloat16;

__device__ __forceinline__ void gld_lds16(const void* g, void* l) {
  __builtin_amdgcn_global_load_lds(
      (const __attribute__((address_space(1))) void*)g,
      (__attribute__((address_space(3))) void*)l, 16, 0, 0);
}

// ---- one-time constants: Mt[q][p] = M[p][q] (transposed for scalar loads), w, scales ----
__global__ void k_setup(const float* __restrict__ t_span, float* __restrict__ Mt,
                        float* __restrict__ wv, float* __restrict__ scales,
                        float* __restrict__ out) {
  __shared__ double Tsh[NC][NP];
  int tid = threadIdx.x;
  for (int idx = tid; idx < NC*NP; idx += 64) {
    int c = idx / NP, p = idx % NP;
    Tsh[c][p] = cos((double)c * (M_PI * ((double)p + 0.5) / NP));
  }
  __syncthreads();
  if (tid < NP) {
    int q = tid;
    double V[NC], K[NC];
    for (int c = 0; c < NC; c++) V[c] = (2.0/NP) * Tsh[c][q];
    V[0] *= 0.5;
    double s = 0.0;
    for (int n = 1; n < NC; n++) {
      double hi = (n+1 < NC) ? V[n+1] : 0.0;
      K[n] = (V[n-1] - hi) / (2.0*n);
      s += (n & 1) ? -K[n] : K[n];
    }
    K[0] = -s;
    double wsum = 0.0;
    for (int c = 0; c < NC; c++) wsum += K[c];
    wv[q] = (float)wsum;
    for (int p = 0; p < NP; p++) {
      double m = 0.0;
      for (int c = 0; c < NC; c++) m += Tsh[c][p] * K[c];
      Mt[q*NP + p] = (float)m;
    }
  }
  if (tid < NI) scales[tid] = 0.5f*(t_span[tid+1]-t_span[tid]);
  if (tid < NI+1) out[tid] = t_span[tid];
}

// ---- weights -> bf16 transposed [n][k] ----
__global__ void k_wt(const float* __restrict__ W1, const float* __restrict__ W2,
                     bf16* __restrict__ W1T, bf16* __restrict__ W2T) {
  int idx = blockIdx.x*256 + threadIdx.x;
  int k = idx >> 9, n = idx & 511;
  W1T[n*DIM + k] = __float2bfloat16(W1[idx]);
  W2T[n*HID + k] = __float2bfloat16(W2[idx]);
}

// ---- init: y0 = y_init, traj[0], Ybf[p][i] = bf16(y_init) ----
__global__ void k_init(const float* __restrict__ y_init, float* __restrict__ y0,
                       bf16* __restrict__ Ybf, float* __restrict__ traj0) {
  int i = blockIdx.x*256 + threadIdx.x;
  float v = y_init[i];
  y0[i] = v; traj0[i] = v;
  bf16 b = __float2bfloat16(v);
  #pragma unroll
  for (int p = 0; p < NP; p++) Ybf[(size_t)p*NELEM + i] = b;
}

// ---- bf16 MFMA GEMM, M=12288 N=512 K=512, 128x128 tile, BK=32, 4 waves ----
// EPI 0: out = bf16(tanh(x + bias));  EPI 1: out = f32(x + bias)
template<int EPI>
__global__ __launch_bounds__(256, 2) void k_gemm(const bf16* __restrict__ A,
    const bf16* __restrict__ BT, const float* __restrict__ bias,
    void* __restrict__ outp) {
  __shared__ bf16 sA[128*32];
  __shared__ bf16 sB[128*32];
  int tid = threadIdx.x;
  int lane = tid & 63, wid = tid >> 6;
  int bm = blockIdx.x >> 2, bn = blockIdx.x & 3;
  int row0 = bm*128, col0 = bn*128;
  int wr = wid >> 1, wc = wid & 1;
  int r16 = lane & 15, g = lane >> 4;

  f32x4 acc[4][4];
  #pragma unroll
  for (int m = 0; m < 4; m++)
    #pragma unroll
    for (int n = 0; n < 4; n++)
      acc[m][n] = {0.f, 0.f, 0.f, 0.f};

  const int cid0 = wid*64 + lane;
  for (int k0 = 0; k0 < DIM; k0 += 32) {
    #pragma unroll
    for (int j = 0; j < 2; j++) {
      int cid = cid0 + j*256;
      gld_lds16(A  + ((size_t)(row0 + (cid>>2)))*DIM + k0 + (cid&3)*8,
                (char*)sA + wid*1024 + j*4096);
      gld_lds16(BT + ((size_t)(col0 + (cid>>2)))*DIM + k0 + (cid&3)*8,
                (char*)sB + wid*1024 + j*4096);
    }
    __syncthreads();
    bf16x8 af[4], bfr[4];
    #pragma unroll
    for (int m = 0; m < 4; m++)
      af[m] = *(const bf16x8*)(sA + (wr*64 + m*16 + r16)*32 + g*8);
    #pragma unroll
    for (int n = 0; n < 4; n++)
      bfr[n] = *(const bf16x8*)(sB + (wc*64 + n*16 + r16)*32 + g*8);
    #pragma unroll
    for (int m = 0; m < 4; m++)
      #pragma unroll
      for (int n = 0; n < 4; n++)
        acc[m][n] = __builtin_amdgcn_mfma_f32_16x16x32_bf16(af[m], bfr[n], acc[m][n], 0, 0, 0);
    __syncthreads();
  }

  #pragma unroll
  for (int m = 0; m < 4; m++) {
    int rowb = row0 + wr*64 + m*16 + g*4;
    #pragma unroll
    for (int n = 0; n < 4; n++) {
      int col = col0 + wc*64 + n*16 + r16;
      float bv = bias[col];
      #pragma unroll
      for (int r = 0; r < 4; r++) {
        float v = acc[m][n][r] + bv;
        if constexpr (EPI == 0) {
          ((bf16*)outp)[(size_t)(rowb + r)*HID + col] = __float2bfloat16(tanhf(v));
        } else {
          ((float*)outp)[(size_t)(rowb + r)*DIM + col] = v;
        }
      }
    }
  }
}

// ---- Picard node update: Ybf[p][i] = bf16(y0[i] + scale * sum_q M[p][q] F[q][i]) ----
__global__ __launch_bounds__(256) void k_combine(const float* __restrict__ F,
    const float* __restrict__ y0, const float* __restrict__ Mt,
    const float* __restrict__ scales, int t, bf16* __restrict__ Ybf) {
  int i = blockIdx.x*256 + threadIdx.x;
  float acc[NP];
  #pragma unroll
  for (int p = 0; p < NP; p++) acc[p] = 0.f;
  for (int q = 0; q < NP; q++) {
    float fq = F[(size_t)q*NELEM + i];
    const float* Mrow = Mt + q*NP;   // uniform address -> s_loads
    #pragma unroll
    for (int p = 0; p < NP; p++) acc[p] = fmaf(Mrow[p], fq, acc[p]);
  }
  float base = y0[i], sc = scales[t];
  #pragma unroll
  for (int p = 0; p < NP; p++)
    Ybf[(size_t)p*NELEM + i] = __float2bfloat16(fmaf(sc, acc[p], base));
}

// ---- interval end: y1 = y0 + scale * w.F ; write traj, reseed y0/Ybf ----
__global__ __launch_bounds__(256) void k_final(const float* __restrict__ F,
    float* __restrict__ y0, const float* __restrict__ wv,
    const float* __restrict__ scales, int t, float* __restrict__ trajout,
    bf16* __restrict__ Ybf, int last) {
  int i = blockIdx.x*256 + threadIdx.x;
  float acc = 0.f;
  for (int q = 0; q < NP; q++) acc = fmaf(wv[q], F[(size_t)q*NELEM + i], acc);
  float y1 = fmaf(scales[t], acc, y0[i]);
  trajout[i] = y1;
  if (!last) {
    y0[i] = y1;
    bf16 b = __float2bfloat16(y1);
    #pragma unroll
    for (int p = 0; p < NP; p++) Ybf[(size_t)p*NELEM + i] = b;
  }
}

extern "C" void kernel_launch(void* const* d_in, const int* in_sizes, int n_in,
                              void* d_out, int out_size, void* d_ws, size_t ws_size,
                              hipStream_t stream) {
  const float* y_init = (const float*)d_in[0];
  const float* t_span = (const float*)d_in[1];
  const float* W1 = (const float*)d_in[2];
  const float* b1 = (const float*)d_in[3];
  const float* W2 = (const float*)d_in[4];
  const float* b2 = (const float*)d_in[5];
  float* out = (float*)d_out;

  char* ws = (char*)d_ws;
  size_t off = 0;
  auto carve = [&](size_t bytes) {
    void* p = ws + off; off += (bytes + 255) & ~(size_t)255; return p;
  };
  float* Mt     = (float*)carve((size_t)NP*NP*4);
  float* wv     = (float*)carve(NP*4);
  float* scales = (float*)carve(8*4);
  float* y0     = (float*)carve((size_t)NELEM*4);
  bf16*  W1T    = (bf16*) carve((size_t)DIM*HID*2);
  bf16*  W2T    = (bf16*) carve((size_t)HID*DIM*2);
  bf16*  Ybf    = (bf16*) carve((size_t)NROW*DIM*2);
  bf16*  Hbf    = (bf16*) carve((size_t)NROW*HID*2);
  float* Fb     = (float*)carve((size_t)NROW*DIM*4);

  k_setup<<<1, 64, 0, stream>>>(t_span, Mt, wv, scales, out);
  k_wt<<<(DIM*HID)/256, 256, 0, stream>>>(W1, W2, W1T, W2T);
  k_init<<<NELEM/256, 256, 0, stream>>>(y_init, y0, Ybf, out + 7);

  for (int t = 0; t < NI; t++) {
    for (int it = 0; it < 5; it++) {
      k_gemm<0><<<(NROW/128)*(HID/128), 256, 0, stream>>>(Ybf, W1T, b1, (void*)Hbf);
      k_gemm<1><<<(NROW/128)*(DIM/128), 256, 0, stream>>>(Hbf, W2T, b2, (void*)Fb);
      if (it < 4)
        k_combine<<<NELEM/256, 256, 0, stream>>>(Fb, y0, Mt, scales, t, Ybf);
      else
        k_final<<<NELEM/256, 256, 0, stream>>>(Fb, y0, wv, scales, t,
            out + 7 + (size_t)(t+1)*NELEM, Ybf, t == NI-1);
    }
  }
}

// Round 2
// 1155.937 us; speedup vs baseline: 1.4679x; 1.4679x over previous
//
#include <hip/hip_runtime.h>
#include <hip/hip_bf16.h>
#include <math.h>

#define NC 24
#define NP 48
#define NI 6
#define BATCH 256
#define DIM 512
#define NROW (NP*BATCH)       // 12288
#define NELEM (BATCH*DIM)     // 131072

typedef __bf16 bf16x8 __attribute__((ext_vector_type(8)));
typedef float f32x4 __attribute__((ext_vector_type(4)));
using bf16 = __hip_bfloat16;

__device__ __forceinline__ void gld_lds16(const void* g, void* l) {
  __builtin_amdgcn_global_load_lds(
      (const __attribute__((address_space(1))) void*)g,
      (__attribute__((address_space(3))) void*)l, 16, 0, 0);
}

__device__ __forceinline__ float fast_tanh(float x) {
  float u = __expf(2.0f * x);                      // v_mul + v_exp_f32
  float r = __builtin_amdgcn_rcpf(u + 1.0f);       // v_add + v_rcp_f32
  return __builtin_fmaf(-2.0f, r, 1.0f);           // inf -> 1, 0 -> -1: exact tails
}

// ---- constants: Mt[q][p] = M[p][q], wv[q], rs[p] = sum_q M[p][q], scales ----
__global__ void k_setup(const float* __restrict__ t_span, float* __restrict__ Mt,
                        float* __restrict__ wv, float* __restrict__ rs,
                        float* __restrict__ scales, float* __restrict__ out) {
  __shared__ double Tsh[NC][NP];
  __shared__ float Msh[NP][NP];     // Msh[p][q]
  int tid = threadIdx.x;
  for (int idx = tid; idx < NC*NP; idx += 64) {
    int c = idx / NP, p = idx % NP;
    Tsh[c][p] = cos((double)c * (M_PI * ((double)p + 0.5) / NP));
  }
  __syncthreads();
  if (tid < NP) {
    int q = tid;
    double V[NC], K[NC];
    for (int c = 0; c < NC; c++) V[c] = (2.0/NP) * Tsh[c][q];
    V[0] *= 0.5;
    double s = 0.0;
    for (int n = 1; n < NC; n++) {
      double hi = (n+1 < NC) ? V[n+1] : 0.0;
      K[n] = (V[n-1] - hi) / (2.0*n);
      s += (n & 1) ? -K[n] : K[n];
    }
    K[0] = -s;
    double wsum = 0.0;
    for (int c = 0; c < NC; c++) wsum += K[c];
    wv[q] = (float)wsum;
    for (int p = 0; p < NP; p++) {
      double m = 0.0;
      for (int c = 0; c < NC; c++) m += Tsh[c][p] * K[c];
      Mt[q*NP + p] = (float)m;
      Msh[p][q] = (float)m;
    }
  }
  __syncthreads();
  if (tid < NP) {
    float s = 0.f;
    for (int q = 0; q < NP; q++) s += Msh[tid][q];
    rs[tid] = s;
  }
  if (tid < NI) scales[tid] = 0.5f*(t_span[tid+1]-t_span[tid]);
  if (tid < NI+1) out[tid] = t_span[tid];
}

// ---- weights -> bf16 transposed [n][k] ----
__global__ void k_wt(const float* __restrict__ W1, const float* __restrict__ W2,
                     bf16* __restrict__ W1T, bf16* __restrict__ W2T) {
  int idx = blockIdx.x*256 + threadIdx.x;
  int k = idx >> 9, n = idx & 511;
  W1T[n*DIM + k] = __float2bfloat16(W1[idx]);
  W2T[n*DIM + k] = __float2bfloat16(W2[idx]);
}

// ---- init: y0, y0bf, traj[0] ----
__global__ void k_init(const float* __restrict__ y_init, float* __restrict__ y0,
                       bf16* __restrict__ y0bf, float* __restrict__ traj0) {
  int i = blockIdx.x*256 + threadIdx.x;
  float v = y_init[i];
  y0[i] = v; traj0[i] = v;
  y0bf[i] = __float2bfloat16(v);
}

// ---- bf16 MFMA GEMM: tile 128x64, BK=64, XOR-swizzled LDS, grid = MB*8 ----
// EPI 0: out = bf16(fast_tanh(x + bias));  EPI 1: out = bf16(x + bias)
template<int EPI>
__global__ __launch_bounds__(256, 3) void k_gemm(const bf16* __restrict__ A,
    const bf16* __restrict__ BT, const float* __restrict__ bias,
    bf16* __restrict__ outp) {
  __shared__ bf16 sA[128*64];
  __shared__ bf16 sB[64*64];
  int tid = threadIdx.x;
  int lane = tid & 63, wid = tid >> 6;
  // XCD-chunked block swizzle (gridDim.x % 8 == 0): blocks sharing an A-panel
  // stay on one XCD's L2.
  int q8 = gridDim.x >> 3;
  int tl = (blockIdx.x & 7)*q8 + (blockIdx.x >> 3);
  int bm = tl >> 3, bn = tl & 7;
  int row0 = bm*128, col0 = bn*64;
  int wr = wid >> 1, wc = wid & 1;
  int r16 = lane & 15, g = lane >> 4;

  f32x4 acc[4][2];
  #pragma unroll
  for (int m = 0; m < 4; m++)
    #pragma unroll
    for (int n = 0; n < 2; n++)
      acc[m][n] = {0.f, 0.f, 0.f, 0.f};

  for (int k0 = 0; k0 < DIM; k0 += 64) {
    // stage A: 128 rows x 64 cols, 8 chunks(16B)/row, source pre-swizzled
    #pragma unroll
    for (int j = 0; j < 4; j++) {
      int cid = wid*64 + lane + j*256;
      int r = cid >> 3;
      int c = (cid & 7) ^ (r & 7);
      gld_lds16(A + (size_t)(row0 + r)*DIM + k0 + c*8,
                (char*)sA + wid*1024 + j*4096);
    }
    // stage B: 64 rows
    #pragma unroll
    for (int j = 0; j < 2; j++) {
      int cid = wid*64 + lane + j*256;
      int r = cid >> 3;
      int c = (cid & 7) ^ (r & 7);
      gld_lds16(BT + (size_t)(col0 + r)*DIM + k0 + c*8,
                (char*)sB + wid*1024 + j*4096);
    }
    __syncthreads();
    #pragma unroll
    for (int kk = 0; kk < 2; kk++) {
      bf16x8 af[4], bfr[2];
      #pragma unroll
      for (int m = 0; m < 4; m++) {
        int r = wr*64 + m*16 + r16;
        af[m] = *(const bf16x8*)(sA + r*64 + (((kk*4+g) ^ (r&7))*8));
      }
      #pragma unroll
      for (int n = 0; n < 2; n++) {
        int r = wc*32 + n*16 + r16;
        bfr[n] = *(const bf16x8*)(sB + r*64 + (((kk*4+g) ^ (r&7))*8));
      }
      #pragma unroll
      for (int m = 0; m < 4; m++)
        #pragma unroll
        for (int n = 0; n < 2; n++)
          acc[m][n] = __builtin_amdgcn_mfma_f32_16x16x32_bf16(af[m], bfr[n], acc[m][n], 0, 0, 0);
    }
    __syncthreads();
  }

  #pragma unroll
  for (int m = 0; m < 4; m++) {
    int rowb = row0 + wr*64 + m*16 + g*4;
    #pragma unroll
    for (int n = 0; n < 2; n++) {
      int col = col0 + wc*32 + n*16 + r16;
      float bv = bias[col];
      #pragma unroll
      for (int r = 0; r < 4; r++) {
        float v = acc[m][n][r] + bv;
        if constexpr (EPI == 0) v = fast_tanh(v);
        outp[(size_t)(rowb + r)*DIM + col] = __float2bfloat16(v);
      }
    }
  }
}

// ---- Picard node update (iters 2..4): Ybf[p][i] = bf16(y0 + sc*sum_q M[p][q]F[q][i]) ----
__global__ __launch_bounds__(256) void k_combine(const bf16* __restrict__ F,
    const float* __restrict__ y0, const float* __restrict__ Mt,
    const float* __restrict__ scales, int t, bf16* __restrict__ Ybf) {
  int i = (blockIdx.x*256 + threadIdx.x)*2;
  float a0[NP], a1[NP];
  #pragma unroll
  for (int p = 0; p < NP; p++) { a0[p] = 0.f; a1[p] = 0.f; }
  for (int q = 0; q < NP; q++) {
    __hip_bfloat162 f = *(const __hip_bfloat162*)(F + (size_t)q*NELEM + i);
    float f0 = __bfloat162float(f.x), f1 = __bfloat162float(f.y);
    const float* Mrow = Mt + q*NP;   // uniform -> s_load
    #pragma unroll
    for (int p = 0; p < NP; p++) {
      a0[p] = fmaf(Mrow[p], f0, a0[p]);
      a1[p] = fmaf(Mrow[p], f1, a1[p]);
    }
  }
  float sc = scales[t];
  float b0 = y0[i], b1 = y0[i+1];
  #pragma unroll
  for (int p = 0; p < NP; p++) {
    __hip_bfloat162 o;
    o.x = __float2bfloat16(fmaf(sc, a0[p], b0));
    o.y = __float2bfloat16(fmaf(sc, a1[p], b1));
    *(__hip_bfloat162*)(Ybf + (size_t)p*NELEM + i) = o;
  }
}

// ---- iter-1 broadcast combine: F same across q -> Ybf[p] = y0 + sc*rs[p]*F0 ----
__global__ __launch_bounds__(256) void k_combine1(const bf16* __restrict__ F0,
    const float* __restrict__ y0, const float* __restrict__ rs,
    const float* __restrict__ scales, int t, bf16* __restrict__ Ybf) {
  int i = (blockIdx.x*256 + threadIdx.x)*2;
  __hip_bfloat162 f = *(const __hip_bfloat162*)(F0 + i);
  float f0 = __bfloat162float(f.x), f1 = __bfloat162float(f.y);
  float sc = scales[t];
  float b0 = y0[i], b1 = y0[i+1];
  #pragma unroll
  for (int p = 0; p < NP; p++) {
    float w = sc * rs[p];
    __hip_bfloat162 o;
    o.x = __float2bfloat16(fmaf(w, f0, b0));
    o.y = __float2bfloat16(fmaf(w, f1, b1));
    *(__hip_bfloat162*)(Ybf + (size_t)p*NELEM + i) = o;
  }
}

// ---- interval end: y1 = y0 + sc * w.F ; write traj, update y0/y0bf ----
__global__ __launch_bounds__(256) void k_final(const bf16* __restrict__ F,
    float* __restrict__ y0, const float* __restrict__ wv,
    const float* __restrict__ scales, int t, float* __restrict__ trajout,
    bf16* __restrict__ y0bf, int last) {
  int i = (blockIdx.x*256 + threadIdx.x)*2;
  float a0 = 0.f, a1 = 0.f;
  for (int q = 0; q < NP; q++) {
    __hip_bfloat162 f = *(const __hip_bfloat162*)(F + (size_t)q*NELEM + i);
    float w = wv[q];
    a0 = fmaf(w, __bfloat162float(f.x), a0);
    a1 = fmaf(w, __bfloat162float(f.y), a1);
  }
  float sc = scales[t];
  float y10 = fmaf(sc, a0, y0[i]);
  float y11 = fmaf(sc, a1, y0[i+1]);
  trajout[i] = y10; trajout[i+1] = y11;
  if (!last) {
    y0[i] = y10; y0[i+1] = y11;
    __hip_bfloat162 o;
    o.x = __float2bfloat16(y10); o.y = __float2bfloat16(y11);
    *(__hip_bfloat162*)(y0bf + i) = o;
  }
}

extern "C" void kernel_launch(void* const* d_in, const int* in_sizes, int n_in,
                              void* d_out, int out_size, void* d_ws, size_t ws_size,
                              hipStream_t stream) {
  const float* y_init = (const float*)d_in[0];
  const float* t_span = (const float*)d_in[1];
  const float* W1 = (const float*)d_in[2];
  const float* b1 = (const float*)d_in[3];
  const float* W2 = (const float*)d_in[4];
  const float* b2 = (const float*)d_in[5];
  float* out = (float*)d_out;

  char* ws = (char*)d_ws;
  size_t off = 0;
  auto carve = [&](size_t bytes) {
    void* p = ws + off; off += (bytes + 255) & ~(size_t)255; return p;
  };
  float* Mt     = (float*)carve((size_t)NP*NP*4);
  float* wv     = (float*)carve(NP*4);
  float* rs     = (float*)carve(NP*4);
  float* scales = (float*)carve(8*4);
  float* y0     = (float*)carve((size_t)NELEM*4);
  bf16*  y0bf   = (bf16*) carve((size_t)NELEM*2);
  bf16*  W1T    = (bf16*) carve((size_t)DIM*DIM*2);
  bf16*  W2T    = (bf16*) carve((size_t)DIM*DIM*2);
  bf16*  Ybf    = (bf16*) carve((size_t)NROW*DIM*2);
  bf16*  Hbf    = (bf16*) carve((size_t)NROW*DIM*2);
  bf16*  Fbf    = (bf16*) carve((size_t)NROW*DIM*2);

  k_setup<<<1, 64, 0, stream>>>(t_span, Mt, wv, rs, scales, out);
  k_wt<<<(DIM*DIM)/256, 256, 0, stream>>>(W1, W2, W1T, W2T);
  k_init<<<NELEM/256, 256, 0, stream>>>(y_init, y0, y0bf, out + 7);

  const int GRID_BIG   = (NROW/128)*8;   // 96*8 = 768 = 3 blocks/CU exact
  const int GRID_SMALL = (BATCH/128)*8;  // 2*8  = 16

  for (int t = 0; t < NI; t++) {
    // Picard iter 1: y_nodes == y0 at all 48 nodes -> 48x smaller GEMMs
    k_gemm<0><<<GRID_SMALL, 256, 0, stream>>>(y0bf, W1T, b1, Hbf);
    k_gemm<1><<<GRID_SMALL, 256, 0, stream>>>(Hbf, W2T, b2, Fbf);
    k_combine1<<<NELEM/512, 256, 0, stream>>>(Fbf, y0, rs, scales, t, Ybf);
    // Picard iters 2..4
    for (int it = 1; it < 4; it++) {
      k_gemm<0><<<GRID_BIG, 256, 0, stream>>>(Ybf, W1T, b1, Hbf);
      k_gemm<1><<<GRID_BIG, 256, 0, stream>>>(Hbf, W2T, b2, Fbf);
      k_combine<<<NELEM/512, 256, 0, stream>>>(Fbf, y0, Mt, scales, t, Ybf);
    }
    // Picard iter 5 + endpoint
    k_gemm<0><<<GRID_BIG, 256, 0, stream>>>(Ybf, W1T, b1, Hbf);
    k_gemm<1><<<GRID_BIG, 256, 0, stream>>>(Hbf, W2T, b2, Fbf);
    k_final<<<NELEM/512, 256, 0, stream>>>(Fbf, y0, wv, scales, t,
        out + 7 + (size_t)(t+1)*NELEM, y0bf, t == NI-1);
  }
}

// Round 3
// 1138.029 us; speedup vs baseline: 1.4910x; 1.0157x over previous
//
#include <hip/hip_runtime.h>
#include <hip/hip_bf16.h>
#include <math.h>

#define NC 24
#define NP 48
#define NI 6
#define BATCH 256
#define DIM 512
#define NROW (NP*BATCH)       // 12288
#define NELEM (BATCH*DIM)     // 131072

typedef __bf16 bf16x8 __attribute__((ext_vector_type(8)));
typedef float f32x4 __attribute__((ext_vector_type(4)));
using bf16 = __hip_bfloat16;

__device__ __forceinline__ void gld_lds16(const void* g, void* l) {
  __builtin_amdgcn_global_load_lds(
      (const __attribute__((address_space(1))) void*)g,
      (__attribute__((address_space(3))) void*)l, 16, 0, 0);
}

__device__ __forceinline__ float fast_tanh(float x) {
  float u = __expf(2.0f * x);
  float r = __builtin_amdgcn_rcpf(u + 1.0f);
  return __builtin_fmaf(-2.0f, r, 1.0f);
}

// ---- constants: Mt[q][p] = M[p][q], wv[q], rs[p] = sum_q M[p][q], scales ----
__global__ void k_setup(const float* __restrict__ t_span, float* __restrict__ Mt,
                        float* __restrict__ wv, float* __restrict__ rs,
                        float* __restrict__ scales, float* __restrict__ out) {
  __shared__ double Tsh[NC][NP];
  __shared__ float Msh[NP][NP];     // Msh[p][q]
  int tid = threadIdx.x;
  for (int idx = tid; idx < NC*NP; idx += 64) {
    int c = idx / NP, p = idx % NP;
    Tsh[c][p] = cos((double)c * (M_PI * ((double)p + 0.5) / NP));
  }
  __syncthreads();
  if (tid < NP) {
    int q = tid;
    double V[NC], K[NC];
    for (int c = 0; c < NC; c++) V[c] = (2.0/NP) * Tsh[c][q];
    V[0] *= 0.5;
    double s = 0.0;
    for (int n = 1; n < NC; n++) {
      double hi = (n+1 < NC) ? V[n+1] : 0.0;
      K[n] = (V[n-1] - hi) / (2.0*n);
      s += (n & 1) ? -K[n] : K[n];
    }
    K[0] = -s;
    double wsum = 0.0;
    for (int c = 0; c < NC; c++) wsum += K[c];
    wv[q] = (float)wsum;
    for (int p = 0; p < NP; p++) {
      double m = 0.0;
      for (int c = 0; c < NC; c++) m += Tsh[c][p] * K[c];
      Mt[q*NP + p] = (float)m;
      Msh[p][q] = (float)m;
    }
  }
  __syncthreads();
  if (tid < NP) {
    float s = 0.f;
    for (int q = 0; q < NP; q++) s += Msh[tid][q];
    rs[tid] = s;
  }
  if (tid < NI) scales[tid] = 0.5f*(t_span[tid+1]-t_span[tid]);
  if (tid < NI+1) out[tid] = t_span[tid];
}

// ---- weights -> bf16 transposed [n][k] ----
__global__ void k_wt(const float* __restrict__ W1, const float* __restrict__ W2,
                     bf16* __restrict__ W1T, bf16* __restrict__ W2T) {
  int idx = blockIdx.x*256 + threadIdx.x;
  int k = idx >> 9, n = idx & 511;
  W1T[n*DIM + k] = __float2bfloat16(W1[idx]);
  W2T[n*DIM + k] = __float2bfloat16(W2[idx]);
}

// ---- init: y0, y0bf, traj[0] ----
__global__ void k_init(const float* __restrict__ y_init, float* __restrict__ y0,
                       bf16* __restrict__ y0bf, float* __restrict__ traj0) {
  int i = blockIdx.x*256 + threadIdx.x;
  float v = y_init[i];
  y0[i] = v; traj0[i] = v;
  y0bf[i] = __float2bfloat16(v);
}

// ---- bf16 MFMA GEMM: tile 128x64, BK=64, double-buffered LDS, counted vmcnt ----
// EPI 0: out = bf16(fast_tanh(x + bias));  EPI 1: out = bf16(x + bias)
template<int EPI>
__global__ __launch_bounds__(256, 3) void k_gemm(const bf16* __restrict__ A,
    const bf16* __restrict__ BT, const float* __restrict__ bias,
    bf16* __restrict__ outp) {
  __shared__ bf16 sA[2][128*64];
  __shared__ bf16 sB[2][64*64];
  int tid = threadIdx.x;
  int lane = tid & 63, wid = tid >> 6;
  // XCD-chunked block swizzle (gridDim.x % 8 == 0)
  int q8 = gridDim.x >> 3;
  int tl = (blockIdx.x & 7)*q8 + (blockIdx.x >> 3);
  int bm = tl >> 3, bn = tl & 7;
  int row0 = bm*128, col0 = bn*64;
  int wr = wid >> 1, wc = wid & 1;
  int r16 = lane & 15, g = lane >> 4;

  f32x4 acc[4][2];
  #pragma unroll
  for (int m = 0; m < 4; m++)
    #pragma unroll
    for (int n = 0; n < 2; n++)
      acc[m][n] = {0.f, 0.f, 0.f, 0.f};

  // stage one K-tile into buffer `buf` (linear LDS dest, pre-swizzled source)
  auto stage = [&](int buf, int k0) {
    #pragma unroll
    for (int j = 0; j < 4; j++) {
      int cid = wid*64 + lane + j*256;
      int r = cid >> 3;
      int c = (cid & 7) ^ (r & 7);
      gld_lds16(A + (size_t)(row0 + r)*DIM + k0 + c*8,
                (char*)&sA[buf][0] + wid*1024 + j*4096);
    }
    #pragma unroll
    for (int j = 0; j < 2; j++) {
      int cid = wid*64 + lane + j*256;
      int r = cid >> 3;
      int c = (cid & 7) ^ (r & 7);
      gld_lds16(BT + (size_t)(col0 + r)*DIM + k0 + c*8,
                (char*)&sB[buf][0] + wid*1024 + j*4096);
    }
  };

  stage(0, 0);                       // prologue: 6 loads in flight
  int cur = 0;
  for (int k0 = 0; k0 < DIM; k0 += 64) {
    if (k0 + 64 < DIM) {
      stage(cur ^ 1, k0 + 64);       // issue next tile (6 more in flight)
      asm volatile("s_waitcnt vmcnt(6)" ::: "memory");  // current tile landed
    } else {
      asm volatile("s_waitcnt vmcnt(0)" ::: "memory");
    }
    __builtin_amdgcn_s_barrier();    // all waves' current tile visible
    #pragma unroll
    for (int kk = 0; kk < 2; kk++) {
      bf16x8 af[4], bfr[2];
      #pragma unroll
      for (int m = 0; m < 4; m++) {
        int r = wr*64 + m*16 + r16;
        af[m] = *(const bf16x8*)(&sA[cur][0] + r*64 + (((kk*4+g) ^ (r&7))*8));
      }
      #pragma unroll
      for (int n = 0; n < 2; n++) {
        int r = wc*32 + n*16 + r16;
        bfr[n] = *(const bf16x8*)(&sB[cur][0] + r*64 + (((kk*4+g) ^ (r&7))*8));
      }
      #pragma unroll
      for (int m = 0; m < 4; m++)
        #pragma unroll
        for (int n = 0; n < 2; n++)
          acc[m][n] = __builtin_amdgcn_mfma_f32_16x16x32_bf16(af[m], bfr[n], acc[m][n], 0, 0, 0);
    }
    __builtin_amdgcn_s_barrier();    // reads of `cur` done before next overwrite
    cur ^= 1;
  }

  #pragma unroll
  for (int m = 0; m < 4; m++) {
    int rowb = row0 + wr*64 + m*16 + g*4;
    #pragma unroll
    for (int n = 0; n < 2; n++) {
      int col = col0 + wc*32 + n*16 + r16;
      float bv = bias[col];
      #pragma unroll
      for (int r = 0; r < 4; r++) {
        float v = acc[m][n][r] + bv;
        if constexpr (EPI == 0) v = fast_tanh(v);
        outp[(size_t)(rowb + r)*DIM + col] = __float2bfloat16(v);
      }
    }
  }
}

// ---- Picard node update (iters 2..4): Ybf[p][i] = bf16(y0 + sc*sum_q M[p][q]F[q][i]) ----
__global__ __launch_bounds__(256) void k_combine(const bf16* __restrict__ F,
    const float* __restrict__ y0, const float* __restrict__ Mt,
    const float* __restrict__ scales, int t, bf16* __restrict__ Ybf) {
  int i = (blockIdx.x*256 + threadIdx.x)*2;
  float a0[NP], a1[NP];
  #pragma unroll
  for (int p = 0; p < NP; p++) { a0[p] = 0.f; a1[p] = 0.f; }
  for (int q = 0; q < NP; q++) {
    __hip_bfloat162 f = *(const __hip_bfloat162*)(F + (size_t)q*NELEM + i);
    float f0 = __bfloat162float(f.x), f1 = __bfloat162float(f.y);
    const float* Mrow = Mt + q*NP;   // uniform -> s_load
    #pragma unroll
    for (int p = 0; p < NP; p++) {
      a0[p] = fmaf(Mrow[p], f0, a0[p]);
      a1[p] = fmaf(Mrow[p], f1, a1[p]);
    }
  }
  float sc = scales[t];
  float b0 = y0[i], b1 = y0[i+1];
  #pragma unroll
  for (int p = 0; p < NP; p++) {
    __hip_bfloat162 o;
    o.x = __float2bfloat16(fmaf(sc, a0[p], b0));
    o.y = __float2bfloat16(fmaf(sc, a1[p], b1));
    *(__hip_bfloat162*)(Ybf + (size_t)p*NELEM + i) = o;
  }
}

// ---- iter-1 broadcast combine: F same across q -> Ybf[p] = y0 + sc*rs[p]*F0 ----
__global__ __launch_bounds__(256) void k_combine1(const bf16* __restrict__ F0,
    const float* __restrict__ y0, const float* __restrict__ rs,
    const float* __restrict__ scales, int t, bf16* __restrict__ Ybf) {
  int i = (blockIdx.x*256 + threadIdx.x)*2;
  __hip_bfloat162 f = *(const __hip_bfloat162*)(F0 + i);
  float f0 = __bfloat162float(f.x), f1 = __bfloat162float(f.y);
  float sc = scales[t];
  float b0 = y0[i], b1 = y0[i+1];
  #pragma unroll
  for (int p = 0; p < NP; p++) {
    float w = sc * rs[p];
    __hip_bfloat162 o;
    o.x = __float2bfloat16(fmaf(w, f0, b0));
    o.y = __float2bfloat16(fmaf(w, f1, b1));
    *(__hip_bfloat162*)(Ybf + (size_t)p*NELEM + i) = o;
  }
}

// ---- interval end: y1 = y0 + sc * w.F ; write traj, update y0/y0bf ----
__global__ __launch_bounds__(256) void k_final(const bf16* __restrict__ F,
    float* __restrict__ y0, const float* __restrict__ wv,
    const float* __restrict__ scales, int t, float* __restrict__ trajout,
    bf16* __restrict__ y0bf, int last) {
  int i = (blockIdx.x*256 + threadIdx.x)*2;
  float a0 = 0.f, a1 = 0.f;
  for (int q = 0; q < NP; q++) {
    __hip_bfloat162 f = *(const __hip_bfloat162*)(F + (size_t)q*NELEM + i);
    float w = wv[q];
    a0 = fmaf(w, __bfloat162float(f.x), a0);
    a1 = fmaf(w, __bfloat162float(f.y), a1);
  }
  float sc = scales[t];
  float y10 = fmaf(sc, a0, y0[i]);
  float y11 = fmaf(sc, a1, y0[i+1]);
  trajout[i] = y10; trajout[i+1] = y11;
  if (!last) {
    y0[i] = y10; y0[i+1] = y11;
    __hip_bfloat162 o;
    o.x = __float2bfloat16(y10); o.y = __float2bfloat16(y11);
    *(__hip_bfloat162*)(y0bf + i) = o;
  }
}

extern "C" void kernel_launch(void* const* d_in, const int* in_sizes, int n_in,
                              void* d_out, int out_size, void* d_ws, size_t ws_size,
                              hipStream_t stream) {
  const float* y_init = (const float*)d_in[0];
  const float* t_span = (const float*)d_in[1];
  const float* W1 = (const float*)d_in[2];
  const float* b1 = (const float*)d_in[3];
  const float* W2 = (const float*)d_in[4];
  const float* b2 = (const float*)d_in[5];
  float* out = (float*)d_out;

  char* ws = (char*)d_ws;
  size_t off = 0;
  auto carve = [&](size_t bytes) {
    void* p = ws + off; off += (bytes + 255) & ~(size_t)255; return p;
  };
  float* Mt     = (float*)carve((size_t)NP*NP*4);
  float* wv     = (float*)carve(NP*4);
  float* rs     = (float*)carve(NP*4);
  float* scales = (float*)carve(8*4);
  float* y0     = (float*)carve((size_t)NELEM*4);
  bf16*  y0bf   = (bf16*) carve((size_t)NELEM*2);
  bf16*  W1T    = (bf16*) carve((size_t)DIM*DIM*2);
  bf16*  W2T    = (bf16*) carve((size_t)DIM*DIM*2);
  bf16*  Ybf    = (bf16*) carve((size_t)NROW*DIM*2);
  bf16*  Hbf    = (bf16*) carve((size_t)NROW*DIM*2);
  bf16*  Fbf    = (bf16*) carve((size_t)NROW*DIM*2);

  k_setup<<<1, 64, 0, stream>>>(t_span, Mt, wv, rs, scales, out);
  k_wt<<<(DIM*DIM)/256, 256, 0, stream>>>(W1, W2, W1T, W2T);
  k_init<<<NELEM/256, 256, 0, stream>>>(y_init, y0, y0bf, out + 7);

  const int GRID_BIG   = (NROW/128)*8;   // 96*8 = 768 = 3 blocks/CU exact
  const int GRID_SMALL = (BATCH/128)*8;  // 2*8  = 16

  for (int t = 0; t < NI; t++) {
    // Picard iter 1: y_nodes == y0 at all 48 nodes -> 48x smaller GEMMs
    k_gemm<0><<<GRID_SMALL, 256, 0, stream>>>(y0bf, W1T, b1, Hbf);
    k_gemm<1><<<GRID_SMALL, 256, 0, stream>>>(Hbf, W2T, b2, Fbf);
    k_combine1<<<NELEM/512, 256, 0, stream>>>(Fbf, y0, rs, scales, t, Ybf);
    // Picard iters 2..4
    for (int it = 1; it < 4; it++) {
      k_gemm<0><<<GRID_BIG, 256, 0, stream>>>(Ybf, W1T, b1, Hbf);
      k_gemm<1><<<GRID_BIG, 256, 0, stream>>>(Hbf, W2T, b2, Fbf);
      k_combine<<<NELEM/512, 256, 0, stream>>>(Fbf, y0, Mt, scales, t, Ybf);
    }
    // Picard iter 5 + endpoint
    k_gemm<0><<<GRID_BIG, 256, 0, stream>>>(Ybf, W1T, b1, Hbf);
    k_gemm<1><<<GRID_BIG, 256, 0, stream>>>(Hbf, W2T, b2, Fbf);
    k_final<<<NELEM/512, 256, 0, stream>>>(Fbf, y0, wv, scales, t,
        out + 7 + (size_t)(t+1)*NELEM, y0bf, t == NI-1);
  }
}

// Round 4
// 983.486 us; speedup vs baseline: 1.7253x; 1.1571x over previous
//
#include <hip/hip_runtime.h>
#include <hip/hip_bf16.h>
#include <math.h>

#define NC 24
#define NP 48
#define NI 6
#define BATCH 256
#define DIM 512
#define NROW (NP*BATCH)       // 12288
#define NELEM (BATCH*DIM)     // 131072

typedef __bf16 bf16x8 __attribute__((ext_vector_type(8)));
typedef float f32x4 __attribute__((ext_vector_type(4)));
using bf16 = __hip_bfloat16;

__device__ __forceinline__ void gld_lds16(const void* g, void* l) {
  __builtin_amdgcn_global_load_lds(
      (const __attribute__((address_space(1))) void*)g,
      (__attribute__((address_space(3))) void*)l, 16, 0, 0);
}

__device__ __forceinline__ float fast_tanh(float x) {
  float u = __expf(2.0f * x);
  float r = __builtin_amdgcn_rcpf(u + 1.0f);
  return __builtin_fmaf(-2.0f, r, 1.0f);
}

// ---- constants: Mt[q][p]=M[p][q], wv, rs[p]=sum_q M[p][q], scales, sumw, zbias ----
__global__ void k_setup(const float* __restrict__ t_span, float* __restrict__ Mt,
                        float* __restrict__ wv, float* __restrict__ rs,
                        float* __restrict__ scales, float* __restrict__ zbias,
                        float* __restrict__ out) {
  __shared__ double Tsh[NC][NP];
  __shared__ float Msh[NP][NP];     // Msh[p][q]
  __shared__ float wsh[NP];
  int tid = threadIdx.x;
  for (int idx = tid; idx < NC*NP; idx += 64) {
    int c = idx / NP, p = idx % NP;
    Tsh[c][p] = cos((double)c * (M_PI * ((double)p + 0.5) / NP));
  }
  __syncthreads();
  if (tid < NP) {
    int q = tid;
    double V[NC], K[NC];
    for (int c = 0; c < NC; c++) V[c] = (2.0/NP) * Tsh[c][q];
    V[0] *= 0.5;
    double s = 0.0;
    for (int n = 1; n < NC; n++) {
      double hi = (n+1 < NC) ? V[n+1] : 0.0;
      K[n] = (V[n-1] - hi) / (2.0*n);
      s += (n & 1) ? -K[n] : K[n];
    }
    K[0] = -s;
    double wsum = 0.0;
    for (int c = 0; c < NC; c++) wsum += K[c];
    wv[q] = (float)wsum;
    wsh[q] = (float)wsum;
    for (int p = 0; p < NP; p++) {
      double m = 0.0;
      for (int c = 0; c < NC; c++) m += Tsh[c][p] * K[c];
      Mt[q*NP + p] = (float)m;
      Msh[p][q] = (float)m;
    }
  }
  __syncthreads();
  if (tid < NP) {
    float s = 0.f;
    for (int q = 0; q < NP; q++) s += Msh[tid][q];
    rs[tid] = s;
  }
  if (tid == 0) {
    float s = 0.f;
    for (int q = 0; q < NP; q++) s += wsh[q];
    scales[6] = s;                               // sumw
  }
  for (int idx = tid; idx < DIM; idx += 64) zbias[idx] = 0.f;
  if (tid < NI) scales[tid] = 0.5f*(t_span[tid+1]-t_span[tid]);
  if (tid < NI+1) out[tid] = t_span[tid];
}

// ---- weights -> bf16: W1T[h][d], W2T[d][h], W2bf[h][d] (straight) ----
__global__ void k_wt(const float* __restrict__ W1, const float* __restrict__ W2,
                     bf16* __restrict__ W1T, bf16* __restrict__ W2T,
                     bf16* __restrict__ W2bf) {
  int idx = blockIdx.x*256 + threadIdx.x;
  int k = idx >> 9, n = idx & 511;
  W1T[n*DIM + k] = __float2bfloat16(W1[idx]);
  W2T[n*DIM + k] = __float2bfloat16(W2[idx]);
  W2bf[idx]      = __float2bfloat16(W2[idx]);
}

// ---- bb[h] = sum_d b2[d] * W1[d][h] ----
__global__ void k_bb(const float* __restrict__ W1, const float* __restrict__ b2,
                     float* __restrict__ bb) {
  int h = blockIdx.x*256 + threadIdx.x;
  float s = 0.f;
  for (int d = 0; d < DIM; d++) s = fmaf(b2[d], W1[d*DIM + h], s);
  bb[h] = s;
}

// ---- init: y0, y0bf, traj[0] ----
__global__ void k_init(const float* __restrict__ y_init, float* __restrict__ y0,
                       bf16* __restrict__ y0bf, float* __restrict__ traj0) {
  int i = blockIdx.x*256 + threadIdx.x;
  float v = y_init[i];
  y0[i] = v; traj0[i] = v;
  y0bf[i] = __float2bfloat16(v);
}

// ---- bf16 MFMA GEMM: tile 128x64, BK=64, dbuf LDS, counted vmcnt, N must be 512 ----
// EPI 1: outb = bf16(acc + bias)
// EPI 2: outf = acc + bias (f32, =C); outb = bf16(tanh(C)) (=H1)
template<int EPI>
__global__ __launch_bounds__(256, 3) void k_gemm(const bf16* __restrict__ A,
    const bf16* __restrict__ BT, const float* __restrict__ bias,
    bf16* __restrict__ outb, float* __restrict__ outf) {
  __shared__ bf16 sA[2][128*64];
  __shared__ bf16 sB[2][64*64];
  int tid = threadIdx.x;
  int lane = tid & 63, wid = tid >> 6;
  int q8 = gridDim.x >> 3;
  int tl = (blockIdx.x & 7)*q8 + (blockIdx.x >> 3);
  int bm = tl >> 3, bn = tl & 7;
  int row0 = bm*128, col0 = bn*64;
  int wr = wid >> 1, wc = wid & 1;
  int r16 = lane & 15, g = lane >> 4;

  f32x4 acc[4][2];
  #pragma unroll
  for (int m = 0; m < 4; m++)
    #pragma unroll
    for (int n = 0; n < 2; n++)
      acc[m][n] = {0.f, 0.f, 0.f, 0.f};

  auto stage = [&](int buf, int k0) {
    #pragma unroll
    for (int j = 0; j < 4; j++) {
      int cid = wid*64 + lane + j*256;
      int r = cid >> 3;
      int c = (cid & 7) ^ (r & 7);
      gld_lds16(A + (size_t)(row0 + r)*DIM + k0 + c*8,
                (char*)&sA[buf][0] + wid*1024 + j*4096);
    }
    #pragma unroll
    for (int j = 0; j < 2; j++) {
      int cid = wid*64 + lane + j*256;
      int r = cid >> 3;
      int c = (cid & 7) ^ (r & 7);
      gld_lds16(BT + (size_t)(col0 + r)*DIM + k0 + c*8,
                (char*)&sB[buf][0] + wid*1024 + j*4096);
    }
  };

  stage(0, 0);
  int cur = 0;
  for (int k0 = 0; k0 < DIM; k0 += 64) {
    if (k0 + 64 < DIM) {
      stage(cur ^ 1, k0 + 64);
      asm volatile("s_waitcnt vmcnt(6)" ::: "memory");
    } else {
      asm volatile("s_waitcnt vmcnt(0)" ::: "memory");
    }
    __builtin_amdgcn_s_barrier();
    #pragma unroll
    for (int kk = 0; kk < 2; kk++) {
      bf16x8 af[4], bfr[2];
      #pragma unroll
      for (int m = 0; m < 4; m++) {
        int r = wr*64 + m*16 + r16;
        af[m] = *(const bf16x8*)(&sA[cur][0] + r*64 + (((kk*4+g) ^ (r&7))*8));
      }
      #pragma unroll
      for (int n = 0; n < 2; n++) {
        int r = wc*32 + n*16 + r16;
        bfr[n] = *(const bf16x8*)(&sB[cur][0] + r*64 + (((kk*4+g) ^ (r&7))*8));
      }
      #pragma unroll
      for (int m = 0; m < 4; m++)
        #pragma unroll
        for (int n = 0; n < 2; n++)
          acc[m][n] = __builtin_amdgcn_mfma_f32_16x16x32_bf16(af[m], bfr[n], acc[m][n], 0, 0, 0);
    }
    __builtin_amdgcn_s_barrier();
    cur ^= 1;
  }

  #pragma unroll
  for (int m = 0; m < 4; m++) {
    int rowb = row0 + wr*64 + m*16 + g*4;
    #pragma unroll
    for (int n = 0; n < 2; n++) {
      int col = col0 + wc*32 + n*16 + r16;
      float bv = bias[col];
      #pragma unroll
      for (int r = 0; r < 4; r++) {
        float v = acc[m][n][r] + bv;
        size_t idx = (size_t)(rowb + r)*DIM + col;
        if constexpr (EPI == 1) {
          outb[idx] = __float2bfloat16(v);
        } else {
          outf[idx] = v;
          outb[idx] = __float2bfloat16(fast_tanh(v));
        }
      }
    }
  }
}

// ---- endpoint GEMM: y1 = y0 + sc*(Hw.W2 + sumw*b2); writes traj, y0, y0bf ----
__global__ __launch_bounds__(256, 3) void k_end(const bf16* __restrict__ A,
    const bf16* __restrict__ BT, const float* __restrict__ b2,
    float* __restrict__ y0, bf16* __restrict__ y0bf,
    const float* __restrict__ scales, int t, float* __restrict__ traj) {
  __shared__ bf16 sA[2][128*64];
  __shared__ bf16 sB[2][64*64];
  int tid = threadIdx.x;
  int lane = tid & 63, wid = tid >> 6;
  int q8 = gridDim.x >> 3;
  int tl = (blockIdx.x & 7)*q8 + (blockIdx.x >> 3);
  int bm = tl >> 3, bn = tl & 7;
  int row0 = bm*128, col0 = bn*64;
  int wr = wid >> 1, wc = wid & 1;
  int r16 = lane & 15, g = lane >> 4;

  f32x4 acc[4][2];
  #pragma unroll
  for (int m = 0; m < 4; m++)
    #pragma unroll
    for (int n = 0; n < 2; n++)
      acc[m][n] = {0.f, 0.f, 0.f, 0.f};

  auto stage = [&](int buf, int k0) {
    #pragma unroll
    for (int j = 0; j < 4; j++) {
      int cid = wid*64 + lane + j*256;
      int r = cid >> 3;
      int c = (cid & 7) ^ (r & 7);
      gld_lds16(A + (size_t)(row0 + r)*DIM + k0 + c*8,
                (char*)&sA[buf][0] + wid*1024 + j*4096);
    }
    #pragma unroll
    for (int j = 0; j < 2; j++) {
      int cid = wid*64 + lane + j*256;
      int r = cid >> 3;
      int c = (cid & 7) ^ (r & 7);
      gld_lds16(BT + (size_t)(col0 + r)*DIM + k0 + c*8,
                (char*)&sB[buf][0] + wid*1024 + j*4096);
    }
  };

  stage(0, 0);
  int cur = 0;
  for (int k0 = 0; k0 < DIM; k0 += 64) {
    if (k0 + 64 < DIM) {
      stage(cur ^ 1, k0 + 64);
      asm volatile("s_waitcnt vmcnt(6)" ::: "memory");
    } else {
      asm volatile("s_waitcnt vmcnt(0)" ::: "memory");
    }
    __builtin_amdgcn_s_barrier();
    #pragma unroll
    for (int kk = 0; kk < 2; kk++) {
      bf16x8 af[4], bfr[2];
      #pragma unroll
      for (int m = 0; m < 4; m++) {
        int r = wr*64 + m*16 + r16;
        af[m] = *(const bf16x8*)(&sA[cur][0] + r*64 + (((kk*4+g) ^ (r&7))*8));
      }
      #pragma unroll
      for (int n = 0; n < 2; n++) {
        int r = wc*32 + n*16 + r16;
        bfr[n] = *(const bf16x8*)(&sB[cur][0] + r*64 + (((kk*4+g) ^ (r&7))*8));
      }
      #pragma unroll
      for (int m = 0; m < 4; m++)
        #pragma unroll
        for (int n = 0; n < 2; n++)
          acc[m][n] = __builtin_amdgcn_mfma_f32_16x16x32_bf16(af[m], bfr[n], acc[m][n], 0, 0, 0);
    }
    __builtin_amdgcn_s_barrier();
    cur ^= 1;
  }

  float sc = scales[t];
  float sumw = scales[6];
  #pragma unroll
  for (int m = 0; m < 4; m++) {
    int rowb = row0 + wr*64 + m*16 + g*4;
    #pragma unroll
    for (int n = 0; n < 2; n++) {
      int col = col0 + wc*32 + n*16 + r16;
      float bv = sumw * b2[col];
      #pragma unroll
      for (int r = 0; r < 4; r++) {
        size_t idx = (size_t)(rowb + r)*DIM + col;
        float y1 = fmaf(sc, acc[m][n][r] + bv, y0[idx]);
        y0[idx] = y1;
        y0bf[idx] = __float2bfloat16(y1);
        traj[idx] = y1;
      }
    }
  }
}

// ---- iter-1 combine: H2[p] = tanh(C + sc*rs[p]*(G1 + bb)) ----
__global__ __launch_bounds__(256) void k_combine1(const bf16* __restrict__ G1,
    const float* __restrict__ C, const float* __restrict__ rs,
    const float* __restrict__ bb, const float* __restrict__ scales, int t,
    bf16* __restrict__ outH) {
  int i = (blockIdx.x*256 + threadIdx.x)*2;
  int h = i & (DIM-1);
  __hip_bfloat162 gb = *(const __hip_bfloat162*)(G1 + i);
  float2 c = *(const float2*)(C + i);
  float g0 = __bfloat162float(gb.x) + bb[h];
  float g1 = __bfloat162float(gb.y) + bb[h+1];
  float sc = scales[t];
  #pragma unroll
  for (int p = 0; p < NP; p++) {
    float w = sc * rs[p];
    __hip_bfloat162 o;
    o.x = __float2bfloat16(fast_tanh(fmaf(w, g0, c.x)));
    o.y = __float2bfloat16(fast_tanh(fmaf(w, g1, c.y)));
    *(__hip_bfloat162*)(outH + (size_t)p*NELEM + i) = o;
  }
}

// ---- Picard combine: Z[p] = C + sc*(M.G)[p] + sc*rs[p]*bb ; H = tanh(Z)
// FIN 0: write 48 H-planes.  FIN 1: write Hw = sum_p wv[p]*tanh(Z[p]) only. ----
template<int FIN>
__global__ __launch_bounds__(256) void k_combine(const bf16* __restrict__ G,
    const float* __restrict__ C, const float* __restrict__ Mt,
    const float* __restrict__ rs, const float* __restrict__ bb,
    const float* __restrict__ wv, const float* __restrict__ scales, int t,
    bf16* __restrict__ outH) {
  int i = (blockIdx.x*256 + threadIdx.x)*2;
  int h = i & (DIM-1);
  float a0[NP], a1[NP];
  #pragma unroll
  for (int p = 0; p < NP; p++) { a0[p] = 0.f; a1[p] = 0.f; }
  for (int q = 0; q < NP; q++) {
    __hip_bfloat162 f = *(const __hip_bfloat162*)(G + (size_t)q*NELEM + i);
    float f0 = __bfloat162float(f.x), f1 = __bfloat162float(f.y);
    const float* Mrow = Mt + q*NP;   // uniform -> s_load
    #pragma unroll
    for (int p = 0; p < NP; p++) {
      a0[p] = fmaf(Mrow[p], f0, a0[p]);
      a1[p] = fmaf(Mrow[p], f1, a1[p]);
    }
  }
  float sc = scales[t];
  float2 c = *(const float2*)(C + i);
  float bb0 = bb[h], bb1 = bb[h+1];
  if constexpr (FIN == 0) {
    #pragma unroll
    for (int p = 0; p < NP; p++) {
      float z0 = fmaf(sc, fmaf(rs[p], bb0, a0[p]), c.x);
      float z1 = fmaf(sc, fmaf(rs[p], bb1, a1[p]), c.y);
      __hip_bfloat162 o;
      o.x = __float2bfloat16(fast_tanh(z0));
      o.y = __float2bfloat16(fast_tanh(z1));
      *(__hip_bfloat162*)(outH + (size_t)p*NELEM + i) = o;
    }
  } else {
    float hw0 = 0.f, hw1 = 0.f;
    #pragma unroll
    for (int p = 0; p < NP; p++) {
      float z0 = fmaf(sc, fmaf(rs[p], bb0, a0[p]), c.x);
      float z1 = fmaf(sc, fmaf(rs[p], bb1, a1[p]), c.y);
      float wp = wv[p];
      hw0 = fmaf(wp, fast_tanh(z0), hw0);
      hw1 = fmaf(wp, fast_tanh(z1), hw1);
    }
    __hip_bfloat162 o;
    o.x = __float2bfloat16(hw0);
    o.y = __float2bfloat16(hw1);
    *(__hip_bfloat162*)(outH + i) = o;
  }
}

extern "C" void kernel_launch(void* const* d_in, const int* in_sizes, int n_in,
                              void* d_out, int out_size, void* d_ws, size_t ws_size,
                              hipStream_t stream) {
  const float* y_init = (const float*)d_in[0];
  const float* t_span = (const float*)d_in[1];
  const float* W1 = (const float*)d_in[2];
  const float* b1 = (const float*)d_in[3];
  const float* W2 = (const float*)d_in[4];
  const float* b2 = (const float*)d_in[5];
  float* out = (float*)d_out;

  char* ws = (char*)d_ws;
  size_t off = 0;
  auto carve = [&](size_t bytes) {
    void* p = ws + off; off += (bytes + 255) & ~(size_t)255; return p;
  };
  float* Mt     = (float*)carve((size_t)NP*NP*4);
  float* wv     = (float*)carve(NP*4);
  float* rs     = (float*)carve(NP*4);
  float* bb     = (float*)carve(DIM*4);
  float* scales = (float*)carve(8*4);
  float* zbias  = (float*)carve(DIM*4);
  float* y0     = (float*)carve((size_t)NELEM*4);
  float* C      = (float*)carve((size_t)NELEM*4);
  bf16*  y0bf   = (bf16*) carve((size_t)NELEM*2);
  bf16*  H1     = (bf16*) carve((size_t)NELEM*2);
  bf16*  Hw     = (bf16*) carve((size_t)NELEM*2);
  bf16*  W1T    = (bf16*) carve((size_t)DIM*DIM*2);
  bf16*  W2T    = (bf16*) carve((size_t)DIM*DIM*2);
  bf16*  W2bf   = (bf16*) carve((size_t)DIM*DIM*2);
  bf16*  W21T   = (bf16*) carve((size_t)DIM*DIM*2);
  bf16*  H      = (bf16*) carve((size_t)NROW*DIM*2);
  bf16*  G      = (bf16*) carve((size_t)NROW*DIM*2);

  k_setup<<<1, 64, 0, stream>>>(t_span, Mt, wv, rs, scales, zbias, out);
  k_wt<<<(DIM*DIM)/256, 256, 0, stream>>>(W1, W2, W1T, W2T, W2bf);
  k_bb<<<2, 256, 0, stream>>>(W1, b2, bb);
  // W21T[h][i] = W21[i][h] = sum_d W2[i][d]*W1[d][h]  (one-time 512^3 GEMM)
  k_gemm<1><<<32, 256, 0, stream>>>(W1T, W2bf, zbias, W21T, nullptr);
  k_init<<<NELEM/256, 256, 0, stream>>>(y_init, y0, y0bf, out + 7);

  const int GRID_BIG   = (NROW/128)*8;    // 768
  const int GRID_SMALL = (BATCH/128)*8;   // 16

  for (int t = 0; t < NI; t++) {
    // C = y0.W1 + b1 (f32), H1 = tanh(C)
    k_gemm<2><<<GRID_SMALL, 256, 0, stream>>>(y0bf, W1T, b1, H1, C);
    // G1 = H1.W21  (small: 256 rows)
    k_gemm<1><<<GRID_SMALL, 256, 0, stream>>>(H1, W21T, zbias, G, nullptr);
    // H2[p] = tanh(C + sc*rs[p]*(G1+bb))
    k_combine1<<<NELEM/512, 256, 0, stream>>>(G, C, rs, bb, scales, t, H);
    // iters 2..4: G = H.W21 ; combine -> next H (last one -> Hw directly)
    for (int s = 0; s < 3; s++) {
      k_gemm<1><<<GRID_BIG, 256, 0, stream>>>(H, W21T, zbias, G, nullptr);
      if (s < 2)
        k_combine<0><<<NELEM/512, 256, 0, stream>>>(G, C, Mt, rs, bb, wv, scales, t, H);
      else
        k_combine<1><<<NELEM/512, 256, 0, stream>>>(G, C, Mt, rs, bb, wv, scales, t, Hw);
    }
    // y1 = y0 + sc*(Hw.W2 + sumw*b2); write traj, update y0/y0bf
    k_end<<<GRID_SMALL, 256, 0, stream>>>(Hw, W2T, b2, y0, y0bf, scales, t,
        out + 7 + (size_t)(t+1)*NELEM);
  }
}

// Round 5
// 592.578 us; speedup vs baseline: 2.8634x; 1.6597x over previous
//
#include <hip/hip_runtime.h>
#include <hip/hip_bf16.h>
#include <math.h>

#define NC 24
#define NP 48
#define NI 6
#define BATCH 256
#define DIM 512
#define NROW (NP*BATCH)       // 12288
#define NELEM (BATCH*DIM)     // 131072

typedef __bf16 bf16x8 __attribute__((ext_vector_type(8)));
typedef float f32x4 __attribute__((ext_vector_type(4)));
using bf16 = __hip_bfloat16;

__device__ __forceinline__ void gld_lds16(const void* g, void* l) {
  __builtin_amdgcn_global_load_lds(
      (const __attribute__((address_space(1))) void*)g,
      (__attribute__((address_space(3))) void*)l, 16, 0, 0);
}

__device__ __forceinline__ float fast_tanh(float x) {
  float u = __expf(2.0f * x);
  float r = __builtin_amdgcn_rcpf(u + 1.0f);
  return __builtin_fmaf(-2.0f, r, 1.0f);
}

// ---- constants: Mt[q][p]=M[p][q], wv, rs[p]=sum_q M[p][q], scales, sumw, zbias ----
__global__ void k_setup(const float* __restrict__ t_span, float* __restrict__ Mt,
                        float* __restrict__ wv, float* __restrict__ rs,
                        float* __restrict__ scales, float* __restrict__ zbias,
                        float* __restrict__ out) {
  __shared__ double Tsh[NC][NP];
  __shared__ float Msh[NP][NP];     // Msh[p][q]
  __shared__ float wsh[NP];
  int tid = threadIdx.x;
  for (int idx = tid; idx < NC*NP; idx += 64) {
    int c = idx / NP, p = idx % NP;
    Tsh[c][p] = cos((double)c * (M_PI * ((double)p + 0.5) / NP));
  }
  __syncthreads();
  if (tid < NP) {
    int q = tid;
    double V[NC], K[NC];
    for (int c = 0; c < NC; c++) V[c] = (2.0/NP) * Tsh[c][q];
    V[0] *= 0.5;
    double s = 0.0;
    for (int n = 1; n < NC; n++) {
      double hi = (n+1 < NC) ? V[n+1] : 0.0;
      K[n] = (V[n-1] - hi) / (2.0*n);
      s += (n & 1) ? -K[n] : K[n];
    }
    K[0] = -s;
    double wsum = 0.0;
    for (int c = 0; c < NC; c++) wsum += K[c];
    wv[q] = (float)wsum;
    wsh[q] = (float)wsum;
    for (int p = 0; p < NP; p++) {
      double m = 0.0;
      for (int c = 0; c < NC; c++) m += Tsh[c][p] * K[c];
      Mt[q*NP + p] = (float)m;
      Msh[p][q] = (float)m;
    }
  }
  __syncthreads();
  if (tid < NP) {
    float s = 0.f;
    for (int q = 0; q < NP; q++) s += Msh[tid][q];
    rs[tid] = s;
  }
  if (tid == 0) {
    float s = 0.f;
    for (int q = 0; q < NP; q++) s += wsh[q];
    scales[6] = s;                               // sumw
  }
  for (int idx = tid; idx < DIM; idx += 64) zbias[idx] = 0.f;
  if (tid < NI) scales[tid] = 0.5f*(t_span[tid+1]-t_span[tid]);
  if (tid < NI+1) out[tid] = t_span[tid];
}

// ---- weights -> bf16: W1T[h][d], W2T[d][h], W2bf[h][d] (straight) ----
__global__ void k_wt(const float* __restrict__ W1, const float* __restrict__ W2,
                     bf16* __restrict__ W1T, bf16* __restrict__ W2T,
                     bf16* __restrict__ W2bf) {
  int idx = blockIdx.x*256 + threadIdx.x;
  int k = idx >> 9, n = idx & 511;
  W1T[n*DIM + k] = __float2bfloat16(W1[idx]);
  W2T[n*DIM + k] = __float2bfloat16(W2[idx]);
  W2bf[idx]      = __float2bfloat16(W2[idx]);
}

// ---- bb[h] = sum_d b2[d] * W1[d][h] ----
__global__ void k_bb(const float* __restrict__ W1, const float* __restrict__ b2,
                     float* __restrict__ bb) {
  int h = blockIdx.x*256 + threadIdx.x;
  float s = 0.f;
  for (int d = 0; d < DIM; d++) s = fmaf(b2[d], W1[d*DIM + h], s);
  bb[h] = s;
}

// ---- init: y0, y0bf, traj[0] ----
__global__ void k_init(const float* __restrict__ y_init, float* __restrict__ y0,
                       bf16* __restrict__ y0bf, float* __restrict__ traj0) {
  int i = blockIdx.x*256 + threadIdx.x;
  float v = y_init[i];
  y0[i] = v; traj0[i] = v;
  y0bf[i] = __float2bfloat16(v);
}

// ---- bf16 MFMA GEMM (small/setup): tile 128x64, BK=64, dbuf, N must be 512 ----
// EPI 1: outb = bf16(acc + bias)
// EPI 2: outf = acc + bias (f32, =C); outb = bf16(tanh(C)) (=H1)
template<int EPI>
__global__ __launch_bounds__(256, 3) void k_gemm(const bf16* __restrict__ A,
    const bf16* __restrict__ BT, const float* __restrict__ bias,
    bf16* __restrict__ outb, float* __restrict__ outf) {
  __shared__ bf16 sA[2][128*64];
  __shared__ bf16 sB[2][64*64];
  int tid = threadIdx.x;
  int lane = tid & 63, wid = tid >> 6;
  int q8 = gridDim.x >> 3;
  int tl = (blockIdx.x & 7)*q8 + (blockIdx.x >> 3);
  int bm = tl >> 3, bn = tl & 7;
  int row0 = bm*128, col0 = bn*64;
  int wr = wid >> 1, wc = wid & 1;
  int r16 = lane & 15, g = lane >> 4;

  f32x4 acc[4][2];
  #pragma unroll
  for (int m = 0; m < 4; m++)
    #pragma unroll
    for (int n = 0; n < 2; n++)
      acc[m][n] = {0.f, 0.f, 0.f, 0.f};

  auto stage = [&](int buf, int k0) {
    #pragma unroll
    for (int j = 0; j < 4; j++) {
      int cid = wid*64 + lane + j*256;
      int r = cid >> 3;
      int c = (cid & 7) ^ (r & 7);
      gld_lds16(A + (size_t)(row0 + r)*DIM + k0 + c*8,
                (char*)&sA[buf][0] + wid*1024 + j*4096);
    }
    #pragma unroll
    for (int j = 0; j < 2; j++) {
      int cid = wid*64 + lane + j*256;
      int r = cid >> 3;
      int c = (cid & 7) ^ (r & 7);
      gld_lds16(BT + (size_t)(col0 + r)*DIM + k0 + c*8,
                (char*)&sB[buf][0] + wid*1024 + j*4096);
    }
  };

  stage(0, 0);
  int cur = 0;
  for (int k0 = 0; k0 < DIM; k0 += 64) {
    if (k0 + 64 < DIM) {
      stage(cur ^ 1, k0 + 64);
      asm volatile("s_waitcnt vmcnt(6)" ::: "memory");
    } else {
      asm volatile("s_waitcnt vmcnt(0)" ::: "memory");
    }
    __builtin_amdgcn_s_barrier();
    #pragma unroll
    for (int kk = 0; kk < 2; kk++) {
      bf16x8 af[4], bfr[2];
      #pragma unroll
      for (int m = 0; m < 4; m++) {
        int r = wr*64 + m*16 + r16;
        af[m] = *(const bf16x8*)(&sA[cur][0] + r*64 + (((kk*4+g) ^ (r&7))*8));
      }
      #pragma unroll
      for (int n = 0; n < 2; n++) {
        int r = wc*32 + n*16 + r16;
        bfr[n] = *(const bf16x8*)(&sB[cur][0] + r*64 + (((kk*4+g) ^ (r&7))*8));
      }
      #pragma unroll
      for (int m = 0; m < 4; m++)
        #pragma unroll
        for (int n = 0; n < 2; n++)
          acc[m][n] = __builtin_amdgcn_mfma_f32_16x16x32_bf16(af[m], bfr[n], acc[m][n], 0, 0, 0);
    }
    __builtin_amdgcn_s_barrier();
    cur ^= 1;
  }

  #pragma unroll
  for (int m = 0; m < 4; m++) {
    int rowb = row0 + wr*64 + m*16 + g*4;
    #pragma unroll
    for (int n = 0; n < 2; n++) {
      int col = col0 + wc*32 + n*16 + r16;
      float bv = bias[col];
      #pragma unroll
      for (int r = 0; r < 4; r++) {
        float v = acc[m][n][r] + bv;
        size_t idx = (size_t)(rowb + r)*DIM + col;
        if constexpr (EPI == 1) {
          outb[idx] = __float2bfloat16(v);
        } else {
          outf[idx] = v;
          outb[idx] = __float2bfloat16(fast_tanh(v));
        }
      }
    }
  }
}

// ---- FUSED Picard iteration: G = H.W21 (MFMA) -> in-LDS combine -> H'/Hw ----
// H layout: row = b*48 + p. Tile 96 rows (2 full b-groups) x 128 cols, BK=64.
// FIN 0: H'[(b,p)][h] = bf16(tanh(C + sc*((M.G)[p] + rs[p]*bb)))
// FIN 1: Hw[b][h] = bf16(sum_p wv[p]*tanh(Z[p]))
template<int FIN>
__global__ __launch_bounds__(256, 2) void k_fused(const bf16* __restrict__ H,
    const bf16* __restrict__ W21T, const float* __restrict__ C,
    const float* __restrict__ Mt, const float* __restrict__ rs,
    const float* __restrict__ bb, const float* __restrict__ wv,
    const float* __restrict__ scales, int t, bf16* __restrict__ outp) {
  __shared__ bf16 sA[2][96*64];     // 24 KB
  __shared__ bf16 sB[2][128*64];    // 32 KB
  __shared__ bf16 sG[96*128];       // 24 KB  (XOR-swizzled)
  int tid = threadIdx.x;
  int lane = tid & 63, wid = tid >> 6;
  // XCD swizzle, grid = 512
  int q8 = gridDim.x >> 3;
  int tl = (blockIdx.x & 7)*q8 + (blockIdx.x >> 3);
  int bm = tl >> 2, bn = tl & 3;
  int row0 = bm*96, col0 = bn*128;
  int wr0 = (wid >> 1)*48, wc0 = (wid & 1)*64;
  int r16 = lane & 15, g = lane >> 4;

  f32x4 acc[3][4];
  #pragma unroll
  for (int m = 0; m < 3; m++)
    #pragma unroll
    for (int n = 0; n < 4; n++)
      acc[m][n] = {0.f, 0.f, 0.f, 0.f};

  // stage: sA 96x64 (3 chunks/thread), sB 128x64 (4 chunks/thread)
  auto stage = [&](int buf, int k0) {
    #pragma unroll
    for (int j = 0; j < 3; j++) {
      int cid = j*256 + tid;
      int r = cid >> 3;
      int c = (cid & 7) ^ (r & 7);
      gld_lds16(H + (size_t)(row0 + r)*DIM + k0 + c*8,
                (char*)&sA[buf][0] + j*4096 + wid*1024);
    }
    #pragma unroll
    for (int j = 0; j < 4; j++) {
      int cid = j*256 + tid;
      int r = cid >> 3;
      int c = (cid & 7) ^ (r & 7);
      gld_lds16(W21T + (size_t)(col0 + r)*DIM + k0 + c*8,
                (char*)&sB[buf][0] + j*4096 + wid*1024);
    }
  };

  stage(0, 0);
  int cur = 0;
  for (int k0 = 0; k0 < DIM; k0 += 64) {
    if (k0 + 64 < DIM) {
      stage(cur ^ 1, k0 + 64);
      asm volatile("s_waitcnt vmcnt(7)" ::: "memory");
    } else {
      asm volatile("s_waitcnt vmcnt(0)" ::: "memory");
    }
    __builtin_amdgcn_s_barrier();
    #pragma unroll
    for (int kk = 0; kk < 2; kk++) {
      bf16x8 af[3], bfr[4];
      #pragma unroll
      for (int m = 0; m < 3; m++) {
        int r = wr0 + m*16 + r16;
        af[m] = *(const bf16x8*)(&sA[cur][0] + r*64 + (((kk*4+g) ^ (r&7))*8));
      }
      #pragma unroll
      for (int n = 0; n < 4; n++) {
        int r = wc0 + n*16 + r16;
        bfr[n] = *(const bf16x8*)(&sB[cur][0] + r*64 + (((kk*4+g) ^ (r&7))*8));
      }
      #pragma unroll
      for (int m = 0; m < 3; m++)
        #pragma unroll
        for (int n = 0; n < 4; n++)
          acc[m][n] = __builtin_amdgcn_mfma_f32_16x16x32_bf16(af[m], bfr[n], acc[m][n], 0, 0, 0);
    }
    __builtin_amdgcn_s_barrier();
    cur ^= 1;
  }

  // ---- write G-tile to LDS (bf16, swizzled: addr ^= ((row>>2)&3)<<5) ----
  #pragma unroll
  for (int m = 0; m < 3; m++) {
    #pragma unroll
    for (int n = 0; n < 4; n++) {
      int col = wc0 + n*16 + r16;
      #pragma unroll
      for (int r = 0; r < 4; r++) {
        int row = wr0 + m*16 + g*4 + r;
        int addr = (row*256 + col*2) ^ (((row>>2)&3)<<5);
        *(bf16*)((char*)sG + addr) = __float2bfloat16(acc[m][n][r]);
      }
    }
  }
  __syncthreads();

  // ---- in-LDS combine: thread owns one (b_loc, h_loc) column ----
  int b_loc = tid >> 7;            // 0..1
  int h_loc = tid & 127;           // 0..127
  int b_glob = bm*2 + b_loc;
  int h_glob = col0 + h_loc;

  float a[NP];
  #pragma unroll
  for (int p = 0; p < NP; p++) a[p] = 0.f;
  for (int q = 0; q < NP; q++) {
    int row = b_loc*48 + q;
    int addr = (row*256 + h_loc*2) ^ (((row>>2)&3)<<5);
    float gq = __bfloat162float(*(const bf16*)((const char*)sG + addr));
    const float* Mrow = Mt + q*NP;   // uniform -> s_load
    #pragma unroll
    for (int p = 0; p < NP; p++) a[p] = fmaf(Mrow[p], gq, a[p]);
  }
  float sc = scales[t];
  float cv = C[(size_t)b_glob*DIM + h_glob];
  float bbv = bb[h_glob];
  if constexpr (FIN == 0) {
    #pragma unroll
    for (int p = 0; p < NP; p++) {
      float z = fmaf(sc, fmaf(rs[p], bbv, a[p]), cv);
      outp[((size_t)b_glob*NP + p)*DIM + h_glob] = __float2bfloat16(fast_tanh(z));
    }
  } else {
    float hw = 0.f;
    #pragma unroll
    for (int p = 0; p < NP; p++) {
      float z = fmaf(sc, fmaf(rs[p], bbv, a[p]), cv);
      hw = fmaf(wv[p], fast_tanh(z), hw);
    }
    outp[(size_t)b_glob*DIM + h_glob] = __float2bfloat16(hw);
  }
}

// ---- endpoint GEMM: y1 = y0 + sc*(Hw.W2 + sumw*b2); writes traj, y0, y0bf ----
__global__ __launch_bounds__(256, 3) void k_end(const bf16* __restrict__ A,
    const bf16* __restrict__ BT, const float* __restrict__ b2,
    float* __restrict__ y0, bf16* __restrict__ y0bf,
    const float* __restrict__ scales, int t, float* __restrict__ traj) {
  __shared__ bf16 sA[2][128*64];
  __shared__ bf16 sB[2][64*64];
  int tid = threadIdx.x;
  int lane = tid & 63, wid = tid >> 6;
  int q8 = gridDim.x >> 3;
  int tl = (blockIdx.x & 7)*q8 + (blockIdx.x >> 3);
  int bm = tl >> 3, bn = tl & 7;
  int row0 = bm*128, col0 = bn*64;
  int wr = wid >> 1, wc = wid & 1;
  int r16 = lane & 15, g = lane >> 4;

  f32x4 acc[4][2];
  #pragma unroll
  for (int m = 0; m < 4; m++)
    #pragma unroll
    for (int n = 0; n < 2; n++)
      acc[m][n] = {0.f, 0.f, 0.f, 0.f};

  auto stage = [&](int buf, int k0) {
    #pragma unroll
    for (int j = 0; j < 4; j++) {
      int cid = wid*64 + lane + j*256;
      int r = cid >> 3;
      int c = (cid & 7) ^ (r & 7);
      gld_lds16(A + (size_t)(row0 + r)*DIM + k0 + c*8,
                (char*)&sA[buf][0] + wid*1024 + j*4096);
    }
    #pragma unroll
    for (int j = 0; j < 2; j++) {
      int cid = wid*64 + lane + j*256;
      int r = cid >> 3;
      int c = (cid & 7) ^ (r & 7);
      gld_lds16(BT + (size_t)(col0 + r)*DIM + k0 + c*8,
                (char*)&sB[buf][0] + wid*1024 + j*4096);
    }
  };

  stage(0, 0);
  int cur = 0;
  for (int k0 = 0; k0 < DIM; k0 += 64) {
    if (k0 + 64 < DIM) {
      stage(cur ^ 1, k0 + 64);
      asm volatile("s_waitcnt vmcnt(6)" ::: "memory");
    } else {
      asm volatile("s_waitcnt vmcnt(0)" ::: "memory");
    }
    __builtin_amdgcn_s_barrier();
    #pragma unroll
    for (int kk = 0; kk < 2; kk++) {
      bf16x8 af[4], bfr[2];
      #pragma unroll
      for (int m = 0; m < 4; m++) {
        int r = wr*64 + m*16 + r16;
        af[m] = *(const bf16x8*)(&sA[cur][0] + r*64 + (((kk*4+g) ^ (r&7))*8));
      }
      #pragma unroll
      for (int n = 0; n < 2; n++) {
        int r = wc*32 + n*16 + r16;
        bfr[n] = *(const bf16x8*)(&sB[cur][0] + r*64 + (((kk*4+g) ^ (r&7))*8));
      }
      #pragma unroll
      for (int m = 0; m < 4; m++)
        #pragma unroll
        for (int n = 0; n < 2; n++)
          acc[m][n] = __builtin_amdgcn_mfma_f32_16x16x32_bf16(af[m], bfr[n], acc[m][n], 0, 0, 0);
    }
    __builtin_amdgcn_s_barrier();
    cur ^= 1;
  }

  float sc = scales[t];
  float sumw = scales[6];
  #pragma unroll
  for (int m = 0; m < 4; m++) {
    int rowb = row0 + wr*64 + m*16 + g*4;
    #pragma unroll
    for (int n = 0; n < 2; n++) {
      int col = col0 + wc*32 + n*16 + r16;
      float bv = sumw * b2[col];
      #pragma unroll
      for (int r = 0; r < 4; r++) {
        size_t idx = (size_t)(rowb + r)*DIM + col;
        float y1 = fmaf(sc, acc[m][n][r] + bv, y0[idx]);
        y0[idx] = y1;
        y0bf[idx] = __float2bfloat16(y1);
        traj[idx] = y1;
      }
    }
  }
}

// ---- iter-1 combine: H2[(b,p)][h] = tanh(C + sc*rs[p]*(G1 + bb)) ----
__global__ __launch_bounds__(256) void k_combine1(const bf16* __restrict__ G1,
    const float* __restrict__ C, const float* __restrict__ rs,
    const float* __restrict__ bb, const float* __restrict__ scales, int t,
    bf16* __restrict__ outH) {
  int i = (blockIdx.x*256 + threadIdx.x)*2;
  int b = i >> 9, h = i & (DIM-1);
  __hip_bfloat162 gb = *(const __hip_bfloat162*)(G1 + i);
  float2 c = *(const float2*)(C + i);
  float g0 = __bfloat162float(gb.x) + bb[h];
  float g1 = __bfloat162float(gb.y) + bb[h+1];
  float sc = scales[t];
  #pragma unroll
  for (int p = 0; p < NP; p++) {
    float w = sc * rs[p];
    __hip_bfloat162 o;
    o.x = __float2bfloat16(fast_tanh(fmaf(w, g0, c.x)));
    o.y = __float2bfloat16(fast_tanh(fmaf(w, g1, c.y)));
    *(__hip_bfloat162*)(outH + ((size_t)b*NP + p)*DIM + h) = o;
  }
}

extern "C" void kernel_launch(void* const* d_in, const int* in_sizes, int n_in,
                              void* d_out, int out_size, void* d_ws, size_t ws_size,
                              hipStream_t stream) {
  const float* y_init = (const float*)d_in[0];
  const float* t_span = (const float*)d_in[1];
  const float* W1 = (const float*)d_in[2];
  const float* b1 = (const float*)d_in[3];
  const float* W2 = (const float*)d_in[4];
  const float* b2 = (const float*)d_in[5];
  float* out = (float*)d_out;

  char* ws = (char*)d_ws;
  size_t off = 0;
  auto carve = [&](size_t bytes) {
    void* p = ws + off; off += (bytes + 255) & ~(size_t)255; return p;
  };
  float* Mt     = (float*)carve((size_t)NP*NP*4);
  float* wv     = (float*)carve(NP*4);
  float* rs     = (float*)carve(NP*4);
  float* bb     = (float*)carve(DIM*4);
  float* scales = (float*)carve(8*4);
  float* zbias  = (float*)carve(DIM*4);
  float* y0     = (float*)carve((size_t)NELEM*4);
  float* C      = (float*)carve((size_t)NELEM*4);
  bf16*  y0bf   = (bf16*) carve((size_t)NELEM*2);
  bf16*  H1     = (bf16*) carve((size_t)NELEM*2);
  bf16*  G1     = (bf16*) carve((size_t)NELEM*2);
  bf16*  Hw     = (bf16*) carve((size_t)NELEM*2);
  bf16*  W1T    = (bf16*) carve((size_t)DIM*DIM*2);
  bf16*  W2T    = (bf16*) carve((size_t)DIM*DIM*2);
  bf16*  W2bf   = (bf16*) carve((size_t)DIM*DIM*2);
  bf16*  W21T   = (bf16*) carve((size_t)DIM*DIM*2);
  bf16*  Ha     = (bf16*) carve((size_t)NROW*DIM*2);
  bf16*  Hb     = (bf16*) carve((size_t)NROW*DIM*2);

  k_setup<<<1, 64, 0, stream>>>(t_span, Mt, wv, rs, scales, zbias, out);
  k_wt<<<(DIM*DIM)/256, 256, 0, stream>>>(W1, W2, W1T, W2T, W2bf);
  k_bb<<<2, 256, 0, stream>>>(W1, b2, bb);
  // W21T[h][i] = (W2.W1)[i][h]  (one-time 512^3 GEMM)
  k_gemm<1><<<32, 256, 0, stream>>>(W1T, W2bf, zbias, W21T, nullptr);
  k_init<<<NELEM/256, 256, 0, stream>>>(y_init, y0, y0bf, out + 7);

  const int GRID_FUSED = (NROW/96)*(DIM/128);  // 128*4 = 512 = 2/CU exact
  const int GRID_SMALL = (BATCH/128)*8;        // 16

  for (int t = 0; t < NI; t++) {
    // C = y0.W1 + b1 (f32), H1 = tanh(C)
    k_gemm<2><<<GRID_SMALL, 256, 0, stream>>>(y0bf, W1T, b1, H1, C);
    // G1 = H1.W21  (small: 256 rows)
    k_gemm<1><<<GRID_SMALL, 256, 0, stream>>>(H1, W21T, zbias, G1, nullptr);
    // H2[(b,p)][h] = tanh(C + sc*rs[p]*(G1+bb))
    k_combine1<<<NELEM/512, 256, 0, stream>>>(G1, C, rs, bb, scales, t, Ha);
    // iters 2..4 fused: GEMM + in-LDS combine
    k_fused<0><<<GRID_FUSED, 256, 0, stream>>>(Ha, W21T, C, Mt, rs, bb, wv, scales, t, Hb);
    k_fused<0><<<GRID_FUSED, 256, 0, stream>>>(Hb, W21T, C, Mt, rs, bb, wv, scales, t, Ha);
    k_fused<1><<<GRID_FUSED, 256, 0, stream>>>(Ha, W21T, C, Mt, rs, bb, wv, scales, t, Hw);
    // y1 = y0 + sc*(Hw.W2 + sumw*b2); write traj, update y0/y0bf
    k_end<<<GRID_SMALL, 256, 0, stream>>>(Hw, W2T, b2, y0, y0bf, scales, t,
        out + 7 + (size_t)(t+1)*NELEM);
  }
}

// Round 6
// 469.945 us; speedup vs baseline: 3.6106x; 1.2610x over previous
//
#include <hip/hip_runtime.h>
#include <hip/hip_bf16.h>
#include <math.h>

#define NC 24
#define NP 48
#define NI 6
#define BATCH 256
#define DIM 512
#define NROW (NP*BATCH)       // 12288
#define NELEM (BATCH*DIM)     // 131072

typedef __bf16 bf16x8 __attribute__((ext_vector_type(8)));
typedef float f32x4 __attribute__((ext_vector_type(4)));
using bf16 = __hip_bfloat16;

struct bq8 { __hip_bfloat162 a, b; };   // 8-byte LDS write

__device__ __forceinline__ void gld_lds16(const void* g, void* l) {
  __builtin_amdgcn_global_load_lds(
      (const __attribute__((address_space(1))) void*)g,
      (__attribute__((address_space(3))) void*)l, 16, 0, 0);
}

__device__ __forceinline__ float fast_tanh(float x) {
  float u = __expf(2.0f * x);
  float r = __builtin_amdgcn_rcpf(u + 1.0f);
  return __builtin_fmaf(-2.0f, r, 1.0f);
}

// ---- constants: Mbf[p][qpad64] bf16, wv, rs[p]=sum_q M[p][q], scales(+sumw), zbias ----
__global__ void k_setup(const float* __restrict__ t_span, bf16* __restrict__ Mbf,
                        float* __restrict__ wv, float* __restrict__ rs,
                        float* __restrict__ scales, float* __restrict__ zbias,
                        float* __restrict__ out) {
  __shared__ double Tsh[NC][NP];
  __shared__ float Msh[NP][NP];     // Msh[p][q]
  __shared__ float wsh[NP];
  int tid = threadIdx.x;
  for (int idx = tid; idx < NC*NP; idx += 64) {
    int c = idx / NP, p = idx % NP;
    Tsh[c][p] = cos((double)c * (M_PI * ((double)p + 0.5) / NP));
  }
  for (int idx = tid; idx < NP*64; idx += 64)
    Mbf[idx] = __float2bfloat16(0.f);
  __syncthreads();
  if (tid < NP) {
    int q = tid;
    double V[NC], K[NC];
    for (int c = 0; c < NC; c++) V[c] = (2.0/NP) * Tsh[c][q];
    V[0] *= 0.5;
    double s = 0.0;
    for (int n = 1; n < NC; n++) {
      double hi = (n+1 < NC) ? V[n+1] : 0.0;
      K[n] = (V[n-1] - hi) / (2.0*n);
      s += (n & 1) ? -K[n] : K[n];
    }
    K[0] = -s;
    double wsum = 0.0;
    for (int c = 0; c < NC; c++) wsum += K[c];
    wv[q] = (float)wsum;
    wsh[q] = (float)wsum;
    for (int p = 0; p < NP; p++) {
      double m = 0.0;
      for (int c = 0; c < NC; c++) m += Tsh[c][p] * K[c];
      Msh[p][q] = (float)m;
      Mbf[p*64 + q] = __float2bfloat16((float)m);
    }
  }
  __syncthreads();
  if (tid < NP) {
    float s = 0.f;
    for (int q = 0; q < NP; q++) s += Msh[tid][q];
    rs[tid] = s;
  }
  if (tid == 0) {
    float s = 0.f;
    for (int q = 0; q < NP; q++) s += wsh[q];
    scales[6] = s;                               // sumw
  }
  for (int idx = tid; idx < DIM; idx += 64) zbias[idx] = 0.f;
  if (tid < NI) scales[tid] = 0.5f*(t_span[tid+1]-t_span[tid]);
  if (tid < NI+1) out[tid] = t_span[tid];
}

// ---- weights -> bf16: W1T[h][d], W2T[d][h], W2bf[h][d] ----
__global__ void k_wt(const float* __restrict__ W1, const float* __restrict__ W2,
                     bf16* __restrict__ W1T, bf16* __restrict__ W2T,
                     bf16* __restrict__ W2bf) {
  int idx = blockIdx.x*256 + threadIdx.x;
  int k = idx >> 9, n = idx & 511;
  W1T[n*DIM + k] = __float2bfloat16(W1[idx]);
  W2T[n*DIM + k] = __float2bfloat16(W2[idx]);
  W2bf[idx]      = __float2bfloat16(W2[idx]);
}

// ---- bb[h] = sum_d b2[d] * W1[d][h] ----
__global__ void k_bb(const float* __restrict__ W1, const float* __restrict__ b2,
                     float* __restrict__ bb) {
  int h = blockIdx.x*256 + threadIdx.x;
  float s = 0.f;
  for (int d = 0; d < DIM; d++) s = fmaf(b2[d], W1[d*DIM + h], s);
  bb[h] = s;
}

// ---- init: y0, y0bf, traj[0] ----
__global__ void k_init(const float* __restrict__ y_init, float* __restrict__ y0,
                       bf16* __restrict__ y0bf, float* __restrict__ traj0) {
  int i = blockIdx.x*256 + threadIdx.x;
  float v = y_init[i];
  y0[i] = v; traj0[i] = v;
  y0bf[i] = __float2bfloat16(v);
}

// ---- generic bf16 MFMA GEMM: tile 128x64, BK=64, dbuf, counted vmcnt ----
// EPI 1: outb = bf16(acc + bias)
// EPI 2: outf = acc + bias (f32, =C); outb = bf16(tanh(C)) (=H1)
template<int EPI>
__global__ __launch_bounds__(256, 3) void k_gemm(const bf16* __restrict__ A,
    const bf16* __restrict__ BT, const float* __restrict__ bias,
    bf16* __restrict__ outb, float* __restrict__ outf) {
  __shared__ bf16 sA[2][128*64];
  __shared__ bf16 sB[2][64*64];
  int tid = threadIdx.x;
  int lane = tid & 63, wid = tid >> 6;
  int q8 = gridDim.x >> 3;
  int tl = (blockIdx.x & 7)*q8 + (blockIdx.x >> 3);
  int bm = tl >> 3, bn = tl & 7;
  int row0 = bm*128, col0 = bn*64;
  int wr = wid >> 1, wc = wid & 1;
  int r16 = lane & 15, g = lane >> 4;

  f32x4 acc[4][2];
  #pragma unroll
  for (int m = 0; m < 4; m++)
    #pragma unroll
    for (int n = 0; n < 2; n++)
      acc[m][n] = {0.f, 0.f, 0.f, 0.f};

  auto stage = [&](int buf, int k0) {
    #pragma unroll
    for (int j = 0; j < 4; j++) {
      int cid = wid*64 + lane + j*256;
      int r = cid >> 3;
      int c = (cid & 7) ^ (r & 7);
      gld_lds16(A + (size_t)(row0 + r)*DIM + k0 + c*8,
                (char*)&sA[buf][0] + wid*1024 + j*4096);
    }
    #pragma unroll
    for (int j = 0; j < 2; j++) {
      int cid = wid*64 + lane + j*256;
      int r = cid >> 3;
      int c = (cid & 7) ^ (r & 7);
      gld_lds16(BT + (size_t)(col0 + r)*DIM + k0 + c*8,
                (char*)&sB[buf][0] + wid*1024 + j*4096);
    }
  };

  stage(0, 0);
  int cur = 0;
  for (int k0 = 0; k0 < DIM; k0 += 64) {
    if (k0 + 64 < DIM) {
      stage(cur ^ 1, k0 + 64);
      asm volatile("s_waitcnt vmcnt(6)" ::: "memory");
    } else {
      asm volatile("s_waitcnt vmcnt(0)" ::: "memory");
    }
    __builtin_amdgcn_s_barrier();
    #pragma unroll
    for (int kk = 0; kk < 2; kk++) {
      bf16x8 af[4], bfr[2];
      #pragma unroll
      for (int m = 0; m < 4; m++) {
        int r = wr*64 + m*16 + r16;
        af[m] = *(const bf16x8*)(&sA[cur][0] + r*64 + (((kk*4+g) ^ (r&7))*8));
      }
      #pragma unroll
      for (int n = 0; n < 2; n++) {
        int r = wc*32 + n*16 + r16;
        bfr[n] = *(const bf16x8*)(&sB[cur][0] + r*64 + (((kk*4+g) ^ (r&7))*8));
      }
      #pragma unroll
      for (int m = 0; m < 4; m++)
        #pragma unroll
        for (int n = 0; n < 2; n++)
          acc[m][n] = __builtin_amdgcn_mfma_f32_16x16x32_bf16(af[m], bfr[n], acc[m][n], 0, 0, 0);
    }
    __builtin_amdgcn_s_barrier();
    cur ^= 1;
  }

  #pragma unroll
  for (int m = 0; m < 4; m++) {
    int rowb = row0 + wr*64 + m*16 + g*4;
    #pragma unroll
    for (int n = 0; n < 2; n++) {
      int col = col0 + wc*32 + n*16 + r16;
      float bv = bias[col];
      #pragma unroll
      for (int r = 0; r < 4; r++) {
        float v = acc[m][n][r] + bv;
        size_t idx = (size_t)(rowb + r)*DIM + col;
        if constexpr (EPI == 1) {
          outb[idx] = __float2bfloat16(v);
        } else {
          outf[idx] = v;
          outb[idx] = __float2bfloat16(fast_tanh(v));
        }
      }
    }
  }
}

// ---- FUSED Picard iter v2: G = H.W21 (MFMA) -> MG = M.G (MFMA) -> tanh epi ----
// H layout row = b*48+p. Tile 96x128 (2 b-groups), 4 waves.
// FIN 0: H'[(b,p)][h] = bf16(tanh(C + sc*(MG[p][h] + rs[p]*bb[h])))
// FIN 1: Hw[b][h] = bf16(sum_p wv[p]*tanh(Z[p][h]))
template<int FIN>
__global__ __launch_bounds__(256, 2) void k_fused(const bf16* __restrict__ H,
    const bf16* __restrict__ W21T, const float* __restrict__ C,
    const bf16* __restrict__ Mbf, const float* __restrict__ rs,
    const float* __restrict__ bb, const float* __restrict__ wv,
    const float* __restrict__ scales, int t, bf16* __restrict__ outp) {
  __shared__ char smem[57344];               // 56 KB union
  bf16* sA = (bf16*)smem;                    // [2][96*64]   24 KB
  bf16* sB = (bf16*)(smem + 24576);          // [2][128*64]  32 KB
  char* sGT = smem;                          // overlay: [h=128][b=2][q=64] bf16, ^((h&7)<<4)
  int tid = threadIdx.x;
  int lane = tid & 63, wid = tid >> 6;
  int q8 = gridDim.x >> 3;
  int tl = (blockIdx.x & 7)*q8 + (blockIdx.x >> 3);
  int bm = tl >> 2, bn = tl & 3;
  int row0 = bm*96, col0 = bn*128;
  int b_w = wid >> 1;                        // wave's b-group (0/1)
  int wr0 = b_w*48, wc0 = (wid & 1)*64;
  int r16 = lane & 15, g = lane >> 4;

  // preload M A-fragments (constant all kernel): af2[pt][kk]
  bf16x8 af2[3][2];
  #pragma unroll
  for (int pt = 0; pt < 3; pt++)
    #pragma unroll
    for (int kk = 0; kk < 2; kk++)
      af2[pt][kk] = *(const bf16x8*)(Mbf + (pt*16 + r16)*64 + kk*32 + g*8);

  f32x4 acc[3][4];
  #pragma unroll
  for (int m = 0; m < 3; m++)
    #pragma unroll
    for (int n = 0; n < 4; n++)
      acc[m][n] = {0.f, 0.f, 0.f, 0.f};

  auto stage = [&](int buf, int k0) {
    #pragma unroll
    for (int j = 0; j < 3; j++) {
      int cid = j*256 + tid;
      int r = cid >> 3;
      int c = (cid & 7) ^ (r & 7);
      gld_lds16(H + (size_t)(row0 + r)*DIM + k0 + c*8,
                (char*)(sA + buf*6144) + j*4096 + wid*1024);
    }
    #pragma unroll
    for (int j = 0; j < 4; j++) {
      int cid = j*256 + tid;
      int r = cid >> 3;
      int c = (cid & 7) ^ (r & 7);
      gld_lds16(W21T + (size_t)(col0 + r)*DIM + k0 + c*8,
                (char*)(sB + buf*8192) + j*4096 + wid*1024);
    }
  };

  stage(0, 0);
  int cur = 0;
  for (int k0 = 0; k0 < DIM; k0 += 64) {
    if (k0 + 64 < DIM) {
      stage(cur ^ 1, k0 + 64);
      asm volatile("s_waitcnt vmcnt(7)" ::: "memory");
    } else {
      asm volatile("s_waitcnt vmcnt(0)" ::: "memory");
    }
    __builtin_amdgcn_s_barrier();
    #pragma unroll
    for (int kk = 0; kk < 2; kk++) {
      bf16x8 af[3], bfr[4];
      #pragma unroll
      for (int m = 0; m < 3; m++) {
        int r = wr0 + m*16 + r16;
        af[m] = *(const bf16x8*)(sA + cur*6144 + r*64 + (((kk*4+g) ^ (r&7))*8));
      }
      #pragma unroll
      for (int n = 0; n < 4; n++) {
        int r = wc0 + n*16 + r16;
        bfr[n] = *(const bf16x8*)(sB + cur*8192 + r*64 + (((kk*4+g) ^ (r&7))*8));
      }
      #pragma unroll
      for (int m = 0; m < 3; m++)
        #pragma unroll
        for (int n = 0; n < 4; n++)
          acc[m][n] = __builtin_amdgcn_mfma_f32_16x16x32_bf16(af[m], bfr[n], acc[m][n], 0, 0, 0);
    }
    __builtin_amdgcn_s_barrier();
    cur ^= 1;
  }

  // ---- staging done; overlay sGT: write G transposed [h][b][q], swizzled ----
  __syncthreads();
  #pragma unroll
  for (int m = 0; m < 3; m++) {
    int qb = m*16 + g*4;                      // q base (4 consecutive via r)
    #pragma unroll
    for (int n = 0; n < 4; n++) {
      int h_loc = wc0 + n*16 + r16;
      int ad = (h_loc*256 + b_w*128 + qb*2) ^ ((h_loc&7)<<4);
      bq8 v;
      v.a = __hip_bfloat162{__float2bfloat16(acc[m][n][0]), __float2bfloat16(acc[m][n][1])};
      v.b = __hip_bfloat162{__float2bfloat16(acc[m][n][2]), __float2bfloat16(acc[m][n][3])};
      *(bq8*)(sGT + ad) = v;
    }
  }
  // zero the q=48..63 pad (M is zero there, but LDS garbage*0 could be NaN)
  {
    int hz = tid >> 1, bz = tid & 1;
    bq8 z; z.a = __hip_bfloat162{__float2bfloat16(0.f), __float2bfloat16(0.f)}; z.b = z.a;
    #pragma unroll
    for (int j = 0; j < 4; j++) {
      int ad = (hz*256 + bz*128 + 96 + j*8) ^ ((hz&7)<<4);
      *(bq8*)(sGT + ad) = z;
    }
  }
  __syncthreads();

  // ---- second MFMA: MG[p][h] = sum_q M[p][q] * G[(b,q)][h] per b-group ----
  int hh = wid & 1;                           // wave's h-half (64 cols)
  f32x4 acc2[3][4];
  #pragma unroll
  for (int m = 0; m < 3; m++)
    #pragma unroll
    for (int n = 0; n < 4; n++)
      acc2[m][n] = {0.f, 0.f, 0.f, 0.f};
  #pragma unroll
  for (int kk = 0; kk < 2; kk++) {
    bf16x8 bfr2[4];
    #pragma unroll
    for (int n2 = 0; n2 < 4; n2++) {
      int h_loc = hh*64 + n2*16 + r16;
      int ad = (h_loc*256 + b_w*128 + (kk*32 + g*8)*2) ^ ((h_loc&7)<<4);
      bfr2[n2] = *(const bf16x8*)(sGT + ad);
    }
    #pragma unroll
    for (int pt = 0; pt < 3; pt++)
      #pragma unroll
      for (int n2 = 0; n2 < 4; n2++)
        acc2[pt][n2] = __builtin_amdgcn_mfma_f32_16x16x32_bf16(af2[pt][kk], bfr2[n2], acc2[pt][n2], 0, 0, 0);
  }

  // ---- epilogue ----
  float sc = scales[t];
  int bglob = bm*2 + b_w;
  float rsv[3][4];
  #pragma unroll
  for (int pt = 0; pt < 3; pt++)
    #pragma unroll
    for (int r = 0; r < 4; r++)
      rsv[pt][r] = rs[pt*16 + g*4 + r];

  #pragma unroll
  for (int n2 = 0; n2 < 4; n2++) {
    int h_glob = col0 + hh*64 + n2*16 + r16;
    float cv = C[(size_t)bglob*DIM + h_glob];
    float bbv = bb[h_glob];
    if constexpr (FIN == 0) {
      #pragma unroll
      for (int pt = 0; pt < 3; pt++) {
        #pragma unroll
        for (int r = 0; r < 4; r++) {
          int p = pt*16 + g*4 + r;
          float z = fmaf(sc, fmaf(rsv[pt][r], bbv, acc2[pt][n2][r]), cv);
          outp[((size_t)bglob*NP + p)*DIM + h_glob] = __float2bfloat16(fast_tanh(z));
        }
      }
    } else {
      float hw = 0.f;
      #pragma unroll
      for (int pt = 0; pt < 3; pt++) {
        #pragma unroll
        for (int r = 0; r < 4; r++) {
          int p = pt*16 + g*4 + r;
          float z = fmaf(sc, fmaf(rsv[pt][r], bbv, acc2[pt][n2][r]), cv);
          hw = fmaf(wv[p], fast_tanh(z), hw);
        }
      }
      hw += __shfl_xor(hw, 16);
      hw += __shfl_xor(hw, 32);
      if (g == 0)
        outp[(size_t)bglob*DIM + h_glob] = __float2bfloat16(hw);
    }
  }
}

// ---- k_next: A=Hw, dual-B GEMM. N-half 0 (W2T): y1/traj/y0/y0bf.
//      N-half 1 (W21T): C += sc*acc + sc*sumw*bb ; H1 = bf16(tanh(C')) ----
__global__ __launch_bounds__(256, 3) void k_next(const bf16* __restrict__ A,
    const bf16* __restrict__ W2T, const bf16* __restrict__ W21T,
    const float* __restrict__ b2, const float* __restrict__ bb,
    float* __restrict__ y0, bf16* __restrict__ y0bf, float* __restrict__ C,
    bf16* __restrict__ H1, const float* __restrict__ scales, int t,
    float* __restrict__ traj) {
  __shared__ bf16 sA[2][128*64];
  __shared__ bf16 sB[2][64*64];
  int tid = threadIdx.x;
  int lane = tid & 63, wid = tid >> 6;
  int q8 = gridDim.x >> 3;                    // 4
  int tl = (blockIdx.x & 7)*q8 + (blockIdx.x >> 3);
  int bm = tl >> 4, bn = tl & 15;
  int half = bn >> 3;                         // 0: W2T, 1: W21T
  int row0 = bm*128, col0 = (bn & 7)*64;
  const bf16* BT = half ? W21T : W2T;
  int wr = wid >> 1, wc = wid & 1;
  int r16 = lane & 15, g = lane >> 4;

  f32x4 acc[4][2];
  #pragma unroll
  for (int m = 0; m < 4; m++)
    #pragma unroll
    for (int n = 0; n < 2; n++)
      acc[m][n] = {0.f, 0.f, 0.f, 0.f};

  auto stage = [&](int buf, int k0) {
    #pragma unroll
    for (int j = 0; j < 4; j++) {
      int cid = wid*64 + lane + j*256;
      int r = cid >> 3;
      int c = (cid & 7) ^ (r & 7);
      gld_lds16(A + (size_t)(row0 + r)*DIM + k0 + c*8,
                (char*)&sA[buf][0] + wid*1024 + j*4096);
    }
    #pragma unroll
    for (int j = 0; j < 2; j++) {
      int cid = wid*64 + lane + j*256;
      int r = cid >> 3;
      int c = (cid & 7) ^ (r & 7);
      gld_lds16(BT + (size_t)(col0 + r)*DIM + k0 + c*8,
                (char*)&sB[buf][0] + wid*1024 + j*4096);
    }
  };

  stage(0, 0);
  int cur = 0;
  for (int k0 = 0; k0 < DIM; k0 += 64) {
    if (k0 + 64 < DIM) {
      stage(cur ^ 1, k0 + 64);
      asm volatile("s_waitcnt vmcnt(6)" ::: "memory");
    } else {
      asm volatile("s_waitcnt vmcnt(0)" ::: "memory");
    }
    __builtin_amdgcn_s_barrier();
    #pragma unroll
    for (int kk = 0; kk < 2; kk++) {
      bf16x8 af[4], bfr[2];
      #pragma unroll
      for (int m = 0; m < 4; m++) {
        int r = wr*64 + m*16 + r16;
        af[m] = *(const bf16x8*)(&sA[cur][0] + r*64 + (((kk*4+g) ^ (r&7))*8));
      }
      #pragma unroll
      for (int n = 0; n < 2; n++) {
        int r = wc*32 + n*16 + r16;
        bfr[n] = *(const bf16x8*)(&sB[cur][0] + r*64 + (((kk*4+g) ^ (r&7))*8));
      }
      #pragma unroll
      for (int m = 0; m < 4; m++)
        #pragma unroll
        for (int n = 0; n < 2; n++)
          acc[m][n] = __builtin_amdgcn_mfma_f32_16x16x32_bf16(af[m], bfr[n], acc[m][n], 0, 0, 0);
    }
    __builtin_amdgcn_s_barrier();
    cur ^= 1;
  }

  float sc = scales[t];
  float sumw = scales[6];
  #pragma unroll
  for (int m = 0; m < 4; m++) {
    int rowb = row0 + wr*64 + m*16 + g*4;
    #pragma unroll
    for (int n = 0; n < 2; n++) {
      int col = col0 + wc*32 + n*16 + r16;
      #pragma unroll
      for (int r = 0; r < 4; r++) {
        size_t idx = (size_t)(rowb + r)*DIM + col;
        if (half == 0) {
          float bv = sumw * b2[col];
          float y1 = fmaf(sc, acc[m][n][r] + bv, y0[idx]);
          y0[idx] = y1;
          y0bf[idx] = __float2bfloat16(y1);
          traj[idx] = y1;
        } else {
          float cb = sc * sumw * bb[col];
          float cnew = fmaf(sc, acc[m][n][r], C[idx] + cb);
          C[idx] = cnew;
          H1[idx] = __float2bfloat16(fast_tanh(cnew));
        }
      }
    }
  }
}

// ---- iter-1 combine: H2[(b,p)][h] = tanh(C + sc*rs[p]*(G1 + bb)) ----
__global__ __launch_bounds__(256) void k_combine1(const bf16* __restrict__ G1,
    const float* __restrict__ C, const float* __restrict__ rs,
    const float* __restrict__ bb, const float* __restrict__ scales, int t,
    bf16* __restrict__ outH) {
  int i = (blockIdx.x*256 + threadIdx.x)*2;
  int b = i >> 9, h = i & (DIM-1);
  __hip_bfloat162 gb = *(const __hip_bfloat162*)(G1 + i);
  float2 c = *(const float2*)(C + i);
  float g0 = __bfloat162float(gb.x) + bb[h];
  float g1 = __bfloat162float(gb.y) + bb[h+1];
  float sc = scales[t];
  #pragma unroll
  for (int p = 0; p < NP; p++) {
    float w = sc * rs[p];
    __hip_bfloat162 o;
    o.x = __float2bfloat16(fast_tanh(fmaf(w, g0, c.x)));
    o.y = __float2bfloat16(fast_tanh(fmaf(w, g1, c.y)));
    *(__hip_bfloat162*)(outH + ((size_t)b*NP + p)*DIM + h) = o;
  }
}

extern "C" void kernel_launch(void* const* d_in, const int* in_sizes, int n_in,
                              void* d_out, int out_size, void* d_ws, size_t ws_size,
                              hipStream_t stream) {
  const float* y_init = (const float*)d_in[0];
  const float* t_span = (const float*)d_in[1];
  const float* W1 = (const float*)d_in[2];
  const float* b1 = (const float*)d_in[3];
  const float* W2 = (const float*)d_in[4];
  const float* b2 = (const float*)d_in[5];
  float* out = (float*)d_out;

  char* ws = (char*)d_ws;
  size_t off = 0;
  auto carve = [&](size_t bytes) {
    void* p = ws + off; off += (bytes + 255) & ~(size_t)255; return p;
  };
  bf16*  Mbf    = (bf16*) carve((size_t)NP*64*2);
  float* wv     = (float*)carve(NP*4);
  float* rs     = (float*)carve(NP*4);
  float* bb     = (float*)carve(DIM*4);
  float* scales = (float*)carve(8*4);
  float* zbias  = (float*)carve(DIM*4);
  float* y0     = (float*)carve((size_t)NELEM*4);
  float* C      = (float*)carve((size_t)NELEM*4);
  bf16*  y0bf   = (bf16*) carve((size_t)NELEM*2);
  bf16*  H1     = (bf16*) carve((size_t)NELEM*2);
  bf16*  G1     = (bf16*) carve((size_t)NELEM*2);
  bf16*  Hw     = (bf16*) carve((size_t)NELEM*2);
  bf16*  W1T    = (bf16*) carve((size_t)DIM*DIM*2);
  bf16*  W2T    = (bf16*) carve((size_t)DIM*DIM*2);
  bf16*  W2bf   = (bf16*) carve((size_t)DIM*DIM*2);
  bf16*  W21T   = (bf16*) carve((size_t)DIM*DIM*2);
  bf16*  Ha     = (bf16*) carve((size_t)NROW*DIM*2);
  bf16*  Hb     = (bf16*) carve((size_t)NROW*DIM*2);

  k_setup<<<1, 64, 0, stream>>>(t_span, Mbf, wv, rs, scales, zbias, out);
  k_wt<<<(DIM*DIM)/256, 256, 0, stream>>>(W1, W2, W1T, W2T, W2bf);
  k_bb<<<2, 256, 0, stream>>>(W1, b2, bb);
  // W21T[h][i] = (W2.W1)[i][h]  (one-time 512^3 GEMM)
  k_gemm<1><<<32, 256, 0, stream>>>(W1T, W2bf, zbias, W21T, nullptr);
  k_init<<<NELEM/256, 256, 0, stream>>>(y_init, y0, y0bf, out + 7);
  // C = y0.W1 + b1 (f32), H1 = tanh(C)  -- interval 0 only; k_next updates later
  k_gemm<2><<<16, 256, 0, stream>>>(y0bf, W1T, b1, H1, C);

  const int GRID_FUSED = (NROW/96)*(DIM/128);  // 512 = 2/CU exact

  for (int t = 0; t < NI; t++) {
    // G1 = H1.W21
    k_gemm<1><<<16, 256, 0, stream>>>(H1, W21T, zbias, G1, nullptr);
    // H(B1)[(b,p)][h] = tanh(C + sc*rs[p]*(G1+bb))
    k_combine1<<<NELEM/512, 256, 0, stream>>>(G1, C, rs, bb, scales, t, Ha);
    // Picard iters 2..4 fused (GEMM + MFMA-combine)
    k_fused<0><<<GRID_FUSED, 256, 0, stream>>>(Ha, W21T, C, Mbf, rs, bb, wv, scales, t, Hb);
    k_fused<0><<<GRID_FUSED, 256, 0, stream>>>(Hb, W21T, C, Mbf, rs, bb, wv, scales, t, Ha);
    k_fused<1><<<GRID_FUSED, 256, 0, stream>>>(Ha, W21T, C, Mbf, rs, bb, wv, scales, t, Hw);
    // y1 (traj/y0/y0bf) and next C/H1 in one dual-B GEMM
    k_next<<<32, 256, 0, stream>>>(Hw, W2T, W21T, b2, bb, y0, y0bf, C, H1,
                                   scales, t, out + 7 + (size_t)(t+1)*NELEM);
  }
}